// Round 1
// baseline (4730.465 us; speedup 1.0000x reference)
//
#include <hip/hip_runtime.h>
#include <math.h>

#define HIDDEN 256
#define NG 50
#define NF 128
#define NCONF 100000
#define NGRAPH 10000
#define ECONF 1000000
#define EGRAPH 30000
#define PI_OVER_CUTOFF 0.3141592653589793f

// ---------------- workspace layout (bytes) ----------------
// agg   [100000*128] f32 : 0          .. 51,200,000
// xf    [100000*128] f32 : 51,200,000 .. 102,400,000   (dead after edge_mlp)
// hmid  [100000*256] f32 : 51,200,000 .. 153,600,000   (overlays xf)
// x_agg [10000*256]  f32 : 153,600,000 .. 163,840,000
// agg_g [10000*256]  f32 : 163,840,000 .. 174,080,000  (later reused as gin_out)
// tbuf  [10000*256]  f32 : 174,080,000 .. 184,320,000  (t, later r)
// ubuf  [10000*256]  f32 : 184,320,000 .. 194,560,000  (u, later v)
// stats                  : 194,560,000 .. +8192  (sums1, ss1, sums2, ss2)
#define AGG_OFF   0ULL
#define XF_OFF    51200000ULL
#define HMID_OFF  51200000ULL
#define XAGG_OFF  153600000ULL
#define AGGG_OFF  163840000ULL
#define TBUF_OFF  174080000ULL
#define UBUF_OFF  184320000ULL
#define STATS_OFF 194560000ULL

// ================= generic fp32 GEMM, 128x128 tile, BK=16, 8x8 micro ==========
// EPI: 0 = acc (+bias if non-null); 1 = relu(acc+bias); 2 = x + acc + bias + gin[batch]
template<int EPI>
__global__ __launch_bounds__(256) void gemm128(
    const float* __restrict__ A, const float* __restrict__ B,
    float* __restrict__ C, int M, int N, int K,
    const float* __restrict__ bias,
    const float* __restrict__ xres, const float* __restrict__ gin,
    const int* __restrict__ batch)
{
    __shared__ float As[16][132];
    __shared__ float Bs[16][132];
    const int bm = blockIdx.x * 128;
    const int bn = blockIdx.y * 128;
    const int tid = threadIdx.x;
    const int ty = tid >> 4;
    const int tx = tid & 15;
    float acc[8][8];
#pragma unroll
    for (int i = 0; i < 8; ++i)
#pragma unroll
        for (int j = 0; j < 8; ++j) acc[i][j] = 0.f;

    for (int k0 = 0; k0 < K; k0 += 16) {
#pragma unroll
        for (int i = 0; i < 2; ++i) {
            int f = tid + i * 256;
            int row = f >> 2;            // 0..127
            int c4 = (f & 3) << 2;       // 0,4,8,12
            int gr = bm + row;
            float4 v = make_float4(0.f, 0.f, 0.f, 0.f);
            if (gr < M) v = *(const float4*)(A + (size_t)gr * K + k0 + c4);
            As[c4 + 0][row] = v.x;
            As[c4 + 1][row] = v.y;
            As[c4 + 2][row] = v.z;
            As[c4 + 3][row] = v.w;
        }
#pragma unroll
        for (int i = 0; i < 2; ++i) {
            int f = tid + i * 256;
            int row = f >> 5;            // 0..15
            int c4 = (f & 31) << 2;      // 0..124
            *(float4*)&Bs[row][c4] = *(const float4*)(B + (size_t)(k0 + row) * N + bn + c4);
        }
        __syncthreads();
#pragma unroll
        for (int k = 0; k < 16; ++k) {
            float a[8], b[8];
            *(float4*)&a[0] = *(const float4*)&As[k][ty * 8];
            *(float4*)&a[4] = *(const float4*)&As[k][ty * 8 + 4];
            *(float4*)&b[0] = *(const float4*)&Bs[k][tx * 8];
            *(float4*)&b[4] = *(const float4*)&Bs[k][tx * 8 + 4];
#pragma unroll
            for (int i = 0; i < 8; ++i)
#pragma unroll
                for (int j = 0; j < 8; ++j)
                    acc[i][j] = fmaf(a[i], b[j], acc[i][j]);
        }
        __syncthreads();
    }

#pragma unroll
    for (int i = 0; i < 8; ++i) {
        int gr = bm + ty * 8 + i;
        if (gr >= M) continue;
        int gb = 0;
        if (EPI == 2) gb = batch[gr];
#pragma unroll
        for (int jj = 0; jj < 2; ++jj) {
            int c0 = bn + tx * 8 + jj * 4;
            float o[4];
#pragma unroll
            for (int q = 0; q < 4; ++q) o[q] = acc[i][jj * 4 + q];
            if (bias != nullptr) {
                float4 bv = *(const float4*)(bias + c0);
                o[0] += bv.x; o[1] += bv.y; o[2] += bv.z; o[3] += bv.w;
            }
            if (EPI == 1) {
#pragma unroll
                for (int q = 0; q < 4; ++q) o[q] = fmaxf(o[q], 0.f);
            }
            if (EPI == 2) {
                float4 xv = *(const float4*)(xres + (size_t)gr * N + c0);
                float4 gv = *(const float4*)(gin + (size_t)gb * N + c0);
                o[0] += xv.x + gv.x; o[1] += xv.y + gv.y;
                o[2] += xv.z + gv.z; o[3] += xv.w + gv.w;
            }
            float4 ov = make_float4(o[0], o[1], o[2], o[3]);
            *(float4*)(C + (size_t)gr * N + c0) = ov;
        }
    }
}

// ============ fused edge MLP + cosine cutoff + gather/scatter ==============
// One block per 64-edge tile. Weights persistent in LDS.
__global__ __launch_bounds__(256) void edge_mlp_scatter(
    const float* __restrict__ EA,   // [ECONF][NG]
    const float* __restrict__ w1,   // [NG][NF]
    const float* __restrict__ b1,   // [NF]
    const float* __restrict__ w2,   // [NF][NF]
    const float* __restrict__ b2,   // [NF]
    const float* __restrict__ ew,   // [ECONF]
    const int*   __restrict__ ei,   // [2][ECONF]
    const float* __restrict__ xf,   // [NCONF][NF]
    float* __restrict__ agg)        // [NCONF][NF]
{
    __shared__ float w1s[NG * NF];      // 25600 B
    __shared__ float b1s[NF];
    __shared__ float w2s[NF * NF];      // 65536 B
    __shared__ float b2s[NF];
    __shared__ float eas[64 * NG];      // 12800 B
    __shared__ float ts[64 * 132];      // 33792 B (padded stride vs bank conflicts)

    const int tid = threadIdx.x;
    for (int i = tid; i < NG * NF / 4; i += 256)
        ((float4*)w1s)[i] = ((const float4*)w1)[i];
    for (int i = tid; i < NF * NF / 4; i += 256)
        ((float4*)w2s)[i] = ((const float4*)w2)[i];
    if (tid < NF / 4) ((float4*)b1s)[tid] = ((const float4*)b1)[tid];
    else if (tid < NF / 2) ((float4*)b2s)[tid - NF / 4] = ((const float4*)b2)[tid - NF / 4];

    const int e0 = blockIdx.x * 64;
    for (int i = tid; i < 64 * NG / 4; i += 256)
        ((float4*)eas)[i] = ((const float4*)(EA + (size_t)e0 * NG))[i];
    __syncthreads();

    const int tr = tid >> 4;   // 0..15 -> 4 edge rows each
    const int tc = tid & 15;   // 0..15 -> 8 cols each

    // ---- layer 1: T = relu(EA @ w1 + b1) ----
    float acc[4][8];
#pragma unroll
    for (int i = 0; i < 4; ++i)
#pragma unroll
        for (int j = 0; j < 8; ++j) acc[i][j] = b1s[tc * 8 + j];
    for (int k = 0; k < NG; ++k) {
        float b[8];
        *(float4*)&b[0] = *(const float4*)&w1s[k * NF + tc * 8];
        *(float4*)&b[4] = *(const float4*)&w1s[k * NF + tc * 8 + 4];
#pragma unroll
        for (int i = 0; i < 4; ++i) {
            float a = eas[(tr * 4 + i) * NG + k];
#pragma unroll
            for (int j = 0; j < 8; ++j) acc[i][j] = fmaf(a, b[j], acc[i][j]);
        }
    }
#pragma unroll
    for (int i = 0; i < 4; ++i) {
#pragma unroll
        for (int jj = 0; jj < 2; ++jj) {
            float4 v;
            v.x = fmaxf(acc[i][jj * 4 + 0], 0.f);
            v.y = fmaxf(acc[i][jj * 4 + 1], 0.f);
            v.z = fmaxf(acc[i][jj * 4 + 2], 0.f);
            v.w = fmaxf(acc[i][jj * 4 + 3], 0.f);
            *(float4*)&ts[(tr * 4 + i) * 132 + tc * 8 + jj * 4] = v;
        }
    }
    __syncthreads();

    // ---- layer 2: W = T @ w2 + b2 ----
    float acc2[4][8];
#pragma unroll
    for (int i = 0; i < 4; ++i)
#pragma unroll
        for (int j = 0; j < 8; ++j) acc2[i][j] = b2s[tc * 8 + j];
    for (int k = 0; k < NF; ++k) {
        float b[8];
        *(float4*)&b[0] = *(const float4*)&w2s[k * NF + tc * 8];
        *(float4*)&b[4] = *(const float4*)&w2s[k * NF + tc * 8 + 4];
#pragma unroll
        for (int i = 0; i < 4; ++i) {
            float a = ts[(tr * 4 + i) * 132 + k];
#pragma unroll
            for (int j = 0; j < 8; ++j) acc2[i][j] = fmaf(a, b[j], acc2[i][j]);
        }
    }

    // ---- epilogue: scale by cutoff-cos, gather xf[src], scatter-add agg[dst] ----
#pragma unroll
    for (int i = 0; i < 4; ++i) {
        int e = e0 + tr * 4 + i;
        int src = ei[e];
        int dst = ei[ECONF + e];
        float cc = 0.5f * (cosf(ew[e] * PI_OVER_CUTOFF) + 1.0f);
        float4 x0 = *(const float4*)(xf + (size_t)src * NF + tc * 8);
        float4 x1 = *(const float4*)(xf + (size_t)src * NF + tc * 8 + 4);
        float xv[8] = { x0.x, x0.y, x0.z, x0.w, x1.x, x1.y, x1.z, x1.w };
        float* ap = agg + (size_t)dst * NF + tc * 8;
#pragma unroll
        for (int j = 0; j < 8; ++j)
            atomicAdd(ap + j, cc * acc2[i][j] * xv[j]);
    }
}

// ================= small kernels =================
__global__ __launch_bounds__(256) void seg_max_k(const float* __restrict__ x,
                                                 float* __restrict__ xagg)
{
    int g = blockIdx.x;
    int c = threadIdx.x;
    float m = -INFINITY;
#pragma unroll
    for (int r = 0; r < NCONF / NGRAPH; ++r)
        m = fmaxf(m, x[((size_t)g * (NCONF / NGRAPH) + r) * HIDDEN + c]);
    xagg[(size_t)g * HIDDEN + c] = m;
}

__global__ __launch_bounds__(256) void gin_edge_k(const float* __restrict__ xagg,
                                                  const float* __restrict__ bemb,
                                                  const int* __restrict__ eig,
                                                  const int* __restrict__ eag,
                                                  float* __restrict__ aggg)
{
    int e = blockIdx.x;
    int c = threadIdx.x;
    int sg = eig[e];
    int dg = eig[EGRAPH + e];
    int f0 = eag[e * 3 + 0];
    int f1 = eag[e * 3 + 1];
    int f2 = eag[e * 3 + 2];
    float v = xagg[(size_t)sg * HIDDEN + c]
            + bemb[(0 * 5 + f0) * HIDDEN + c]
            + bemb[(1 * 5 + f1) * HIDDEN + c]
            + bemb[(2 * 5 + f2) * HIDDEN + c];
    v = fmaxf(v, 0.f);
    atomicAdd(&aggg[(size_t)dg * HIDDEN + c], v);
}

__global__ __launch_bounds__(256) void gin_t_k(const float* __restrict__ xagg,
                                               const float* __restrict__ aggg,
                                               const float* __restrict__ epsp,
                                               float* __restrict__ t)
{
    int idx = blockIdx.x * 256 + threadIdx.x;     // over float4
    float e1 = 1.f + epsp[0];
    float4 a = ((const float4*)xagg)[idx];
    float4 g = ((const float4*)aggg)[idx];
    float4 o = make_float4(e1 * a.x + g.x, e1 * a.y + g.y, e1 * a.z + g.z, e1 * a.w + g.w);
    ((float4*)t)[idx] = o;
}

__global__ __launch_bounds__(256) void bn_stats_k(const float* __restrict__ u, int M,
                                                  float* __restrict__ sums)
{
    int c = threadIdx.x;
    int r0 = blockIdx.x * 256;
    int rend = min(r0 + 256, M);
    float s = 0.f, s2 = 0.f;
    for (int r = r0; r < rend; ++r) {
        float v = u[(size_t)r * HIDDEN + c];
        s += v;
        s2 = fmaf(v, v, s2);
    }
    atomicAdd(&sums[c], s);
    atomicAdd(&sums[HIDDEN + c], s2);
}

__global__ __launch_bounds__(256) void bn_final_k(const float* __restrict__ sums,
                                                  const float* __restrict__ g,
                                                  const float* __restrict__ b,
                                                  int M, float* __restrict__ ss)
{
    int c = threadIdx.x;
    float mean = sums[c] / (float)M;
    float var = sums[HIDDEN + c] / (float)M - mean * mean;
    float sc = g[c] / sqrtf(var + 1e-5f);
    ss[c] = sc;
    ss[HIDDEN + c] = b[c] - mean * sc;
}

template<bool RELU>
__global__ __launch_bounds__(256) void bn_apply_k(const float* __restrict__ u,
                                                  const float* __restrict__ ss,
                                                  float* __restrict__ out)
{
    int idx = blockIdx.x * 256 + threadIdx.x;     // over float4
    int c4 = (idx & (HIDDEN / 4 - 1)) * 4;
    float4 v = ((const float4*)u)[idx];
    float4 sc = *(const float4*)&ss[c4];
    float4 sh = *(const float4*)&ss[HIDDEN + c4];
    float4 o = make_float4(v.x * sc.x + sh.x, v.y * sc.y + sh.y,
                           v.z * sc.z + sh.z, v.w * sc.w + sh.w);
    if (RELU) {
        o.x = fmaxf(o.x, 0.f); o.y = fmaxf(o.y, 0.f);
        o.z = fmaxf(o.z, 0.f); o.w = fmaxf(o.w, 0.f);
    }
    ((float4*)out)[idx] = o;
}

// ================= launch =================
extern "C" void kernel_launch(void* const* d_in, const int* in_sizes, int n_in,
                              void* d_out, int out_size, void* d_ws, size_t ws_size,
                              hipStream_t stream)
{
    const float* x        = (const float*)d_in[0];
    const int*   cnb      = (const int*)d_in[1];
    const int*   eic      = (const int*)d_in[2];
    const float* ewc      = (const float*)d_in[3];
    const float* eac      = (const float*)d_in[4];
    const int*   eig      = (const int*)d_in[5];
    const int*   eag      = (const int*)d_in[6];
    const float* mlp_w1   = (const float*)d_in[7];
    const float* mlp_b1   = (const float*)d_in[8];
    const float* mlp_w2   = (const float*)d_in[9];
    const float* mlp_b2   = (const float*)d_in[10];
    const float* cf_lin1  = (const float*)d_in[11];
    const float* cf_lin2  = (const float*)d_in[12];
    const float* cf_lin2b = (const float*)d_in[13];
    const float* lin_w    = (const float*)d_in[14];
    const float* lin_b    = (const float*)d_in[15];
    const float* bond_emb = (const float*)d_in[16];
    const float* gin_eps  = (const float*)d_in[17];
    const float* gin_w1   = (const float*)d_in[18];
    const float* gin_b1   = (const float*)d_in[19];
    const float* bn1_g    = (const float*)d_in[20];
    const float* bn1_b    = (const float*)d_in[21];
    const float* gin_w2   = (const float*)d_in[22];
    const float* gin_b2   = (const float*)d_in[23];
    const float* bn2_g    = (const float*)d_in[24];
    const float* bn2_b    = (const float*)d_in[25];
    float* out = (float*)d_out;

    char* ws = (char*)d_ws;
    float* agg   = (float*)(ws + AGG_OFF);
    float* xf    = (float*)(ws + XF_OFF);
    float* hmid  = (float*)(ws + HMID_OFF);
    float* xagg  = (float*)(ws + XAGG_OFF);
    float* aggg  = (float*)(ws + AGGG_OFF);
    float* tbuf  = (float*)(ws + TBUF_OFF);
    float* ubuf  = (float*)(ws + UBUF_OFF);
    float* sums1 = (float*)(ws + STATS_OFF);
    float* ss1   = (float*)(ws + STATS_OFF + 2048);
    float* sums2 = (float*)(ws + STATS_OFF + 4096);
    float* ss2   = (float*)(ws + STATS_OFF + 6144);
    float* gout  = aggg;  // reuse agg_g after t is computed

    hipMemsetAsync(agg, 0, (size_t)NCONF * NF * 4, stream);
    hipMemsetAsync(aggg, 0, (size_t)NGRAPH * HIDDEN * 4, stream);
    hipMemsetAsync(sums1, 0, 8192, stream);

    // GIN pooling (reads x only)
    seg_max_k<<<NGRAPH, 256, 0, stream>>>(x, xagg);

    // CFConv: xf = x @ cf_lin1
    gemm128<0><<<dim3(782, 1), 256, 0, stream>>>(x, cf_lin1, xf, NCONF, NF, HIDDEN,
                                                 nullptr, nullptr, nullptr, nullptr);
    // fused filter MLP + scatter
    edge_mlp_scatter<<<ECONF / 64, 256, 0, stream>>>(eac, mlp_w1, mlp_b1, mlp_w2, mlp_b2,
                                                     ewc, eic, xf, agg);
    // hmid = relu(agg @ cf_lin2 + b)
    gemm128<1><<<dim3(782, 2), 256, 0, stream>>>(agg, cf_lin2, hmid, NCONF, HIDDEN, NF,
                                                 cf_lin2b, nullptr, nullptr, nullptr);

    // GIN branch
    gin_edge_k<<<EGRAPH, 256, 0, stream>>>(xagg, bond_emb, eig, eag, aggg);
    gin_t_k<<<NGRAPH * HIDDEN / 4 / 256, 256, 0, stream>>>(xagg, aggg, gin_eps, tbuf);
    gemm128<0><<<dim3(79, 2), 256, 0, stream>>>(tbuf, gin_w1, ubuf, NGRAPH, HIDDEN, HIDDEN,
                                                gin_b1, nullptr, nullptr, nullptr);
    bn_stats_k<<<(NGRAPH + 255) / 256, 256, 0, stream>>>(ubuf, NGRAPH, sums1);
    bn_final_k<<<1, 256, 0, stream>>>(sums1, bn1_g, bn1_b, NGRAPH, ss1);
    bn_apply_k<true><<<NGRAPH * HIDDEN / 4 / 256, 256, 0, stream>>>(ubuf, ss1, tbuf);
    gemm128<0><<<dim3(79, 2), 256, 0, stream>>>(tbuf, gin_w2, ubuf, NGRAPH, HIDDEN, HIDDEN,
                                                gin_b2, nullptr, nullptr, nullptr);
    bn_stats_k<<<(NGRAPH + 255) / 256, 256, 0, stream>>>(ubuf, NGRAPH, sums2);
    bn_final_k<<<1, 256, 0, stream>>>(sums2, bn2_g, bn2_b, NGRAPH, ss2);
    bn_apply_k<false><<<NGRAPH * HIDDEN / 4 / 256, 256, 0, stream>>>(ubuf, ss2, gout);

    // final: out = x + hmid @ lin_w + lin_b + gout[batch]
    gemm128<2><<<dim3(782, 2), 256, 0, stream>>>(hmid, lin_w, out, NCONF, HIDDEN, HIDDEN,
                                                 lin_b, x, gout, cnb);
}

// Round 2
// 2057.552 us; speedup vs baseline: 2.2991x; 2.2991x over previous
//
#include <hip/hip_runtime.h>
#include <hip/hip_bf16.h>
#include <math.h>

#define HIDDEN 256
#define NG 50
#define NF 128
#define NCONF 100000
#define NGRAPH 10000
#define ECONF 1000000
#define EGRAPH 30000
#define PI_OVER_CUTOFF 0.3141592653589793f
#define NBLK 391                 // ceil(NCONF/256) for scan

// ---------------- BIG workspace layout (bytes) ----------------
#define AGG_OFF    0ULL            // 100000*128*4 = 51,200,000
#define XF_OFF     51200000ULL     // 100000*128*4
#define WBUF_OFF   102400000ULL    // 1M*128*2 bf16 = 256,000,000 (dead after gather)
#define HMID_OFF   102400000ULL    // 100000*256*4 overlays dead WBUF
#define XAGG_OFF   358400000ULL
#define AGGG_OFF   368640000ULL
#define TBUF_OFF   378880000ULL
#define UBUF_OFF   389120000ULL
#define STATS_OFF  399360000ULL    // 8192
#define DEG_OFF    399368192ULL    // 400000
#define START_OFF  399768192ULL    // 400000
#define CURS_OFF   400168192ULL    // 400000
#define BSUM_OFF   400568192ULL    // 2048
#define SSRC_OFF   400570240ULL    // 4,000,000
#define SEID_OFF   404570240ULL    // 4,000,000
#define WS_NEEDED  408570240ULL

// ---------------- SMALL (fallback) layout = round-1 ----------------
#define S_AGG_OFF   0ULL
#define S_XF_OFF    51200000ULL
#define S_HMID_OFF  51200000ULL
#define S_XAGG_OFF  153600000ULL
#define S_AGGG_OFF  163840000ULL
#define S_TBUF_OFF  174080000ULL
#define S_UBUF_OFF  184320000ULL
#define S_STATS_OFF 194560000ULL

// ================= generic fp32 GEMM, 128x128 tile, BK=16, 8x8 micro ==========
template<int EPI>
__global__ __launch_bounds__(256) void gemm128(
    const float* __restrict__ A, const float* __restrict__ B,
    float* __restrict__ C, int M, int N, int K,
    const float* __restrict__ bias,
    const float* __restrict__ xres, const float* __restrict__ gin,
    const int* __restrict__ batch)
{
    __shared__ float As[16][132];
    __shared__ float Bs[16][132];
    const int bm = blockIdx.x * 128;
    const int bn = blockIdx.y * 128;
    const int tid = threadIdx.x;
    const int ty = tid >> 4;
    const int tx = tid & 15;
    float acc[8][8];
#pragma unroll
    for (int i = 0; i < 8; ++i)
#pragma unroll
        for (int j = 0; j < 8; ++j) acc[i][j] = 0.f;

    for (int k0 = 0; k0 < K; k0 += 16) {
#pragma unroll
        for (int i = 0; i < 2; ++i) {
            int f = tid + i * 256;
            int row = f >> 2;
            int c4 = (f & 3) << 2;
            int gr = bm + row;
            float4 v = make_float4(0.f, 0.f, 0.f, 0.f);
            if (gr < M) v = *(const float4*)(A + (size_t)gr * K + k0 + c4);
            As[c4 + 0][row] = v.x;
            As[c4 + 1][row] = v.y;
            As[c4 + 2][row] = v.z;
            As[c4 + 3][row] = v.w;
        }
#pragma unroll
        for (int i = 0; i < 2; ++i) {
            int f = tid + i * 256;
            int row = f >> 5;
            int c4 = (f & 31) << 2;
            *(float4*)&Bs[row][c4] = *(const float4*)(B + (size_t)(k0 + row) * N + bn + c4);
        }
        __syncthreads();
#pragma unroll
        for (int k = 0; k < 16; ++k) {
            float a[8], b[8];
            *(float4*)&a[0] = *(const float4*)&As[k][ty * 8];
            *(float4*)&a[4] = *(const float4*)&As[k][ty * 8 + 4];
            *(float4*)&b[0] = *(const float4*)&Bs[k][tx * 8];
            *(float4*)&b[4] = *(const float4*)&Bs[k][tx * 8 + 4];
#pragma unroll
            for (int i = 0; i < 8; ++i)
#pragma unroll
                for (int j = 0; j < 8; ++j)
                    acc[i][j] = fmaf(a[i], b[j], acc[i][j]);
        }
        __syncthreads();
    }

#pragma unroll
    for (int i = 0; i < 8; ++i) {
        int gr = bm + ty * 8 + i;
        if (gr >= M) continue;
        int gb = 0;
        if (EPI == 2) gb = batch[gr];
#pragma unroll
        for (int jj = 0; jj < 2; ++jj) {
            int c0 = bn + tx * 8 + jj * 4;
            float o[4];
#pragma unroll
            for (int q = 0; q < 4; ++q) o[q] = acc[i][jj * 4 + q];
            if (bias != nullptr) {
                float4 bv = *(const float4*)(bias + c0);
                o[0] += bv.x; o[1] += bv.y; o[2] += bv.z; o[3] += bv.w;
            }
            if (EPI == 1) {
#pragma unroll
                for (int q = 0; q < 4; ++q) o[q] = fmaxf(o[q], 0.f);
            }
            if (EPI == 2) {
                float4 xv = *(const float4*)(xres + (size_t)gr * N + c0);
                float4 gv = *(const float4*)(gin + (size_t)gb * N + c0);
                o[0] += xv.x + gv.x; o[1] += xv.y + gv.y;
                o[2] += xv.z + gv.z; o[3] += xv.w + gv.w;
            }
            *(float4*)(C + (size_t)gr * N + c0) = make_float4(o[0], o[1], o[2], o[3]);
        }
    }
}

// ===================== CSR build =====================
__global__ __launch_bounds__(256) void hist_k(const int* __restrict__ ei,
                                              int* __restrict__ deg)
{
    int e = blockIdx.x * 256 + threadIdx.x;
    if (e < ECONF) atomicAdd(&deg[ei[ECONF + e]], 1);
}

__global__ __launch_bounds__(256) void scanA_k(const int* __restrict__ deg,
                                               int* __restrict__ excl,
                                               int* __restrict__ bsum)
{
    __shared__ int s[256];
    int tid = threadIdx.x;
    int i = blockIdx.x * 256 + tid;
    int v = (i < NCONF) ? deg[i] : 0;
    s[tid] = v;
    __syncthreads();
#pragma unroll
    for (int off = 1; off < 256; off <<= 1) {
        int t = (tid >= off) ? s[tid - off] : 0;
        __syncthreads();
        s[tid] += t;
        __syncthreads();
    }
    if (i < NCONF) excl[i] = s[tid] - v;
    if (tid == 255) bsum[blockIdx.x] = s[255];
}

__global__ __launch_bounds__(512) void scanB_k(int* __restrict__ bsum)
{
    __shared__ int s[512];
    int tid = threadIdx.x;
    int v = (tid < NBLK) ? bsum[tid] : 0;
    s[tid] = v;
    __syncthreads();
#pragma unroll
    for (int off = 1; off < 512; off <<= 1) {
        int t = (tid >= off) ? s[tid - off] : 0;
        __syncthreads();
        s[tid] += t;
        __syncthreads();
    }
    if (tid < NBLK) bsum[tid] = s[tid] - v;   // exclusive block offsets, in place
}

__global__ __launch_bounds__(256) void scanC_k(int* __restrict__ excl,
                                               const int* __restrict__ bsum)
{
    int i = blockIdx.x * 256 + threadIdx.x;
    if (i < NCONF) excl[i] += bsum[blockIdx.x];
}

__global__ __launch_bounds__(256) void fill_csr_k(const int* __restrict__ ei,
                                                  const int* __restrict__ startx,
                                                  int* __restrict__ cursor,
                                                  int* __restrict__ ssrc,
                                                  int* __restrict__ seid)
{
    int e = blockIdx.x * 256 + threadIdx.x;
    if (e >= ECONF) return;
    int src = ei[e];
    int dst = ei[ECONF + e];
    int pos = atomicAdd(&cursor[dst], 1);
    int slot = startx[dst] + pos;
    ssrc[slot] = src;
    seid[slot] = e;
}

// ============ edge MLP -> bf16 W buffer (cutoff folded in) ==============
// 64 edges/block, weights streamed from L1/L2, LDS = union(eas, ts) = 33.8 KB
__global__ __launch_bounds__(256) void edge_mlp_k(
    const float* __restrict__ EA, const float* __restrict__ w1,
    const float* __restrict__ b1, const float* __restrict__ w2,
    const float* __restrict__ b2, const float* __restrict__ ew,
    ushort* __restrict__ Wout)
{
    __shared__ float smem[64 * 132];      // eas[64][50] then ts[64][132]
    float* eas = smem;
    float* ts = smem;

    const int tid = threadIdx.x;
    const int e0 = blockIdx.x * 64;
    for (int i = tid; i < 64 * NG / 4; i += 256)
        ((float4*)eas)[i] = ((const float4*)(EA + (size_t)e0 * NG))[i];
    __syncthreads();

    const int tr = tid >> 4;   // 0..15 -> 4 edge rows each
    const int tc = tid & 15;   // 0..15 -> 8 cols each

    // ---- layer 1: T = relu(EA @ w1 + b1) ----
    float acc[4][8];
    {
        float4 bv0 = *(const float4*)(b1 + tc * 8);
        float4 bv1 = *(const float4*)(b1 + tc * 8 + 4);
        float bb[8] = { bv0.x, bv0.y, bv0.z, bv0.w, bv1.x, bv1.y, bv1.z, bv1.w };
#pragma unroll
        for (int i = 0; i < 4; ++i)
#pragma unroll
            for (int j = 0; j < 8; ++j) acc[i][j] = bb[j];
    }
    for (int k = 0; k < NG; ++k) {
        float b[8];
        *(float4*)&b[0] = *(const float4*)(w1 + k * NF + tc * 8);
        *(float4*)&b[4] = *(const float4*)(w1 + k * NF + tc * 8 + 4);
#pragma unroll
        for (int i = 0; i < 4; ++i) {
            float a = eas[(tr * 4 + i) * NG + k];
#pragma unroll
            for (int j = 0; j < 8; ++j) acc[i][j] = fmaf(a, b[j], acc[i][j]);
        }
    }
    __syncthreads();   // eas dead, reuse as ts
#pragma unroll
    for (int i = 0; i < 4; ++i) {
#pragma unroll
        for (int jj = 0; jj < 2; ++jj) {
            float4 v;
            v.x = fmaxf(acc[i][jj * 4 + 0], 0.f);
            v.y = fmaxf(acc[i][jj * 4 + 1], 0.f);
            v.z = fmaxf(acc[i][jj * 4 + 2], 0.f);
            v.w = fmaxf(acc[i][jj * 4 + 3], 0.f);
            *(float4*)&ts[(tr * 4 + i) * 132 + tc * 8 + jj * 4] = v;
        }
    }
    __syncthreads();

    // ---- layer 2: W = T @ w2 + b2 ----
    float acc2[4][8];
    {
        float4 bv0 = *(const float4*)(b2 + tc * 8);
        float4 bv1 = *(const float4*)(b2 + tc * 8 + 4);
        float bb[8] = { bv0.x, bv0.y, bv0.z, bv0.w, bv1.x, bv1.y, bv1.z, bv1.w };
#pragma unroll
        for (int i = 0; i < 4; ++i)
#pragma unroll
            for (int j = 0; j < 8; ++j) acc2[i][j] = bb[j];
    }
    for (int k = 0; k < NF; ++k) {
        float b[8];
        *(float4*)&b[0] = *(const float4*)(w2 + k * NF + tc * 8);
        *(float4*)&b[4] = *(const float4*)(w2 + k * NF + tc * 8 + 4);
#pragma unroll
        for (int i = 0; i < 4; ++i) {
            float a = ts[(tr * 4 + i) * 132 + k];
#pragma unroll
            for (int j = 0; j < 8; ++j) acc2[i][j] = fmaf(a, b[j], acc2[i][j]);
        }
    }

    // ---- epilogue: scale by cosine cutoff, store bf16 ----
#pragma unroll
    for (int i = 0; i < 4; ++i) {
        int e = e0 + tr * 4 + i;
        float cc = 0.5f * (cosf(ew[e] * PI_OVER_CUTOFF) + 1.0f);
        union { ushort u[8]; uint4 v; } pk;
#pragma unroll
        for (int j = 0; j < 8; ++j) {
            __hip_bfloat16 h = __float2bfloat16(cc * acc2[i][j]);
            pk.u[j] = *(ushort*)&h;
        }
        *(uint4*)(Wout + (size_t)e * NF + tc * 8) = pk.v;
    }
}

// ============ deterministic gather: agg[d] = sum_e W[e] * xf[src[e]] ============
__global__ __launch_bounds__(256) void gather_k(
    const int* __restrict__ startx, const int* __restrict__ deg,
    const int* __restrict__ seid, const int* __restrict__ ssrc,
    const __hip_bfloat16* __restrict__ Wbuf, const float* __restrict__ xf,
    float* __restrict__ agg)
{
    int d = blockIdx.x * 2 + (threadIdx.x >> 7);
    int c = threadIdx.x & 127;
    int s0 = startx[d];
    int n = deg[d];
    float acc = 0.f;
    for (int i = 0; i < n; ++i) {
        int e = seid[s0 + i];
        int src = ssrc[s0 + i];
        float w = __bfloat162float(Wbuf[(size_t)e * NF + c]);
        acc = fmaf(w, xf[(size_t)src * NF + c], acc);
    }
    agg[(size_t)d * NF + c] = acc;
}

// ============ fallback: round-1 fused atomic kernel (small ws only) ==========
__global__ __launch_bounds__(256) void edge_mlp_scatter(
    const float* __restrict__ EA, const float* __restrict__ w1,
    const float* __restrict__ b1, const float* __restrict__ w2,
    const float* __restrict__ b2, const float* __restrict__ ew,
    const int* __restrict__ ei, const float* __restrict__ xf,
    float* __restrict__ agg)
{
    __shared__ float w1s[NG * NF];
    __shared__ float b1s[NF];
    __shared__ float w2s[NF * NF];
    __shared__ float b2s[NF];
    __shared__ float eas[64 * NG];
    __shared__ float ts[64 * 132];

    const int tid = threadIdx.x;
    for (int i = tid; i < NG * NF / 4; i += 256)
        ((float4*)w1s)[i] = ((const float4*)w1)[i];
    for (int i = tid; i < NF * NF / 4; i += 256)
        ((float4*)w2s)[i] = ((const float4*)w2)[i];
    if (tid < NF / 4) ((float4*)b1s)[tid] = ((const float4*)b1)[tid];
    else if (tid < NF / 2) ((float4*)b2s)[tid - NF / 4] = ((const float4*)b2)[tid - NF / 4];

    const int e0 = blockIdx.x * 64;
    for (int i = tid; i < 64 * NG / 4; i += 256)
        ((float4*)eas)[i] = ((const float4*)(EA + (size_t)e0 * NG))[i];
    __syncthreads();

    const int tr = tid >> 4;
    const int tc = tid & 15;

    float acc[4][8];
#pragma unroll
    for (int i = 0; i < 4; ++i)
#pragma unroll
        for (int j = 0; j < 8; ++j) acc[i][j] = b1s[tc * 8 + j];
    for (int k = 0; k < NG; ++k) {
        float b[8];
        *(float4*)&b[0] = *(const float4*)&w1s[k * NF + tc * 8];
        *(float4*)&b[4] = *(const float4*)&w1s[k * NF + tc * 8 + 4];
#pragma unroll
        for (int i = 0; i < 4; ++i) {
            float a = eas[(tr * 4 + i) * NG + k];
#pragma unroll
            for (int j = 0; j < 8; ++j) acc[i][j] = fmaf(a, b[j], acc[i][j]);
        }
    }
#pragma unroll
    for (int i = 0; i < 4; ++i)
#pragma unroll
        for (int jj = 0; jj < 2; ++jj) {
            float4 v;
            v.x = fmaxf(acc[i][jj * 4 + 0], 0.f);
            v.y = fmaxf(acc[i][jj * 4 + 1], 0.f);
            v.z = fmaxf(acc[i][jj * 4 + 2], 0.f);
            v.w = fmaxf(acc[i][jj * 4 + 3], 0.f);
            *(float4*)&ts[(tr * 4 + i) * 132 + tc * 8 + jj * 4] = v;
        }
    __syncthreads();

    float acc2[4][8];
#pragma unroll
    for (int i = 0; i < 4; ++i)
#pragma unroll
        for (int j = 0; j < 8; ++j) acc2[i][j] = b2s[tc * 8 + j];
    for (int k = 0; k < NF; ++k) {
        float b[8];
        *(float4*)&b[0] = *(const float4*)&w2s[k * NF + tc * 8];
        *(float4*)&b[4] = *(const float4*)&w2s[k * NF + tc * 8 + 4];
#pragma unroll
        for (int i = 0; i < 4; ++i) {
            float a = ts[(tr * 4 + i) * 132 + k];
#pragma unroll
            for (int j = 0; j < 8; ++j) acc2[i][j] = fmaf(a, b[j], acc2[i][j]);
        }
    }

#pragma unroll
    for (int i = 0; i < 4; ++i) {
        int e = e0 + tr * 4 + i;
        int src = ei[e];
        int dst = ei[ECONF + e];
        float cc = 0.5f * (cosf(ew[e] * PI_OVER_CUTOFF) + 1.0f);
        float4 x0 = *(const float4*)(xf + (size_t)src * NF + tc * 8);
        float4 x1 = *(const float4*)(xf + (size_t)src * NF + tc * 8 + 4);
        float xv[8] = { x0.x, x0.y, x0.z, x0.w, x1.x, x1.y, x1.z, x1.w };
        float* ap = agg + (size_t)dst * NF + tc * 8;
#pragma unroll
        for (int j = 0; j < 8; ++j)
            atomicAdd(ap + j, cc * acc2[i][j] * xv[j]);
    }
}

// ================= small kernels =================
__global__ __launch_bounds__(256) void seg_max_k(const float* __restrict__ x,
                                                 float* __restrict__ xagg)
{
    int g = blockIdx.x;
    int c = threadIdx.x;
    float m = -INFINITY;
#pragma unroll
    for (int r = 0; r < NCONF / NGRAPH; ++r)
        m = fmaxf(m, x[((size_t)g * (NCONF / NGRAPH) + r) * HIDDEN + c]);
    xagg[(size_t)g * HIDDEN + c] = m;
}

__global__ __launch_bounds__(256) void gin_edge_k(const float* __restrict__ xagg,
                                                  const float* __restrict__ bemb,
                                                  const int* __restrict__ eig,
                                                  const int* __restrict__ eag,
                                                  float* __restrict__ aggg)
{
    int e = blockIdx.x;
    int c = threadIdx.x;
    int sg = eig[e];
    int dg = eig[EGRAPH + e];
    int f0 = eag[e * 3 + 0];
    int f1 = eag[e * 3 + 1];
    int f2 = eag[e * 3 + 2];
    float v = xagg[(size_t)sg * HIDDEN + c]
            + bemb[(0 * 5 + f0) * HIDDEN + c]
            + bemb[(1 * 5 + f1) * HIDDEN + c]
            + bemb[(2 * 5 + f2) * HIDDEN + c];
    v = fmaxf(v, 0.f);
    atomicAdd(&aggg[(size_t)dg * HIDDEN + c], v);
}

__global__ __launch_bounds__(256) void gin_t_k(const float* __restrict__ xagg,
                                               const float* __restrict__ aggg,
                                               const float* __restrict__ epsp,
                                               float* __restrict__ t)
{
    int idx = blockIdx.x * 256 + threadIdx.x;
    float e1 = 1.f + epsp[0];
    float4 a = ((const float4*)xagg)[idx];
    float4 g = ((const float4*)aggg)[idx];
    ((float4*)t)[idx] = make_float4(e1 * a.x + g.x, e1 * a.y + g.y,
                                    e1 * a.z + g.z, e1 * a.w + g.w);
}

__global__ __launch_bounds__(256) void bn_stats_k(const float* __restrict__ u, int M,
                                                  float* __restrict__ sums)
{
    int c = threadIdx.x;
    int r0 = blockIdx.x * 256;
    int rend = min(r0 + 256, M);
    float s = 0.f, s2 = 0.f;
    for (int r = r0; r < rend; ++r) {
        float v = u[(size_t)r * HIDDEN + c];
        s += v;
        s2 = fmaf(v, v, s2);
    }
    atomicAdd(&sums[c], s);
    atomicAdd(&sums[HIDDEN + c], s2);
}

__global__ __launch_bounds__(256) void bn_final_k(const float* __restrict__ sums,
                                                  const float* __restrict__ g,
                                                  const float* __restrict__ b,
                                                  int M, float* __restrict__ ss)
{
    int c = threadIdx.x;
    float mean = sums[c] / (float)M;
    float var = sums[HIDDEN + c] / (float)M - mean * mean;
    float sc = g[c] / sqrtf(var + 1e-5f);
    ss[c] = sc;
    ss[HIDDEN + c] = b[c] - mean * sc;
}

template<bool RELU>
__global__ __launch_bounds__(256) void bn_apply_k(const float* __restrict__ u,
                                                  const float* __restrict__ ss,
                                                  float* __restrict__ out)
{
    int idx = blockIdx.x * 256 + threadIdx.x;
    int c4 = (idx & (HIDDEN / 4 - 1)) * 4;
    float4 v = ((const float4*)u)[idx];
    float4 sc = *(const float4*)&ss[c4];
    float4 sh = *(const float4*)&ss[HIDDEN + c4];
    float4 o = make_float4(v.x * sc.x + sh.x, v.y * sc.y + sh.y,
                           v.z * sc.z + sh.z, v.w * sc.w + sh.w);
    if (RELU) {
        o.x = fmaxf(o.x, 0.f); o.y = fmaxf(o.y, 0.f);
        o.z = fmaxf(o.z, 0.f); o.w = fmaxf(o.w, 0.f);
    }
    ((float4*)out)[idx] = o;
}

// ================= launch =================
extern "C" void kernel_launch(void* const* d_in, const int* in_sizes, int n_in,
                              void* d_out, int out_size, void* d_ws, size_t ws_size,
                              hipStream_t stream)
{
    const float* x        = (const float*)d_in[0];
    const int*   cnb      = (const int*)d_in[1];
    const int*   eic      = (const int*)d_in[2];
    const float* ewc      = (const float*)d_in[3];
    const float* eac      = (const float*)d_in[4];
    const int*   eig      = (const int*)d_in[5];
    const int*   eag      = (const int*)d_in[6];
    const float* mlp_w1   = (const float*)d_in[7];
    const float* mlp_b1   = (const float*)d_in[8];
    const float* mlp_w2   = (const float*)d_in[9];
    const float* mlp_b2   = (const float*)d_in[10];
    const float* cf_lin1  = (const float*)d_in[11];
    const float* cf_lin2  = (const float*)d_in[12];
    const float* cf_lin2b = (const float*)d_in[13];
    const float* lin_w    = (const float*)d_in[14];
    const float* lin_b    = (const float*)d_in[15];
    const float* bond_emb = (const float*)d_in[16];
    const float* gin_eps  = (const float*)d_in[17];
    const float* gin_w1   = (const float*)d_in[18];
    const float* gin_b1   = (const float*)d_in[19];
    const float* bn1_g    = (const float*)d_in[20];
    const float* bn1_b    = (const float*)d_in[21];
    const float* gin_w2   = (const float*)d_in[22];
    const float* gin_b2   = (const float*)d_in[23];
    const float* bn2_g    = (const float*)d_in[24];
    const float* bn2_b    = (const float*)d_in[25];
    float* out = (float*)d_out;

    char* ws = (char*)d_ws;
    const bool big = (ws_size >= WS_NEEDED);

    float* agg, *xf, *hmid, *xagg, *aggg, *tbuf, *ubuf, *sums1, *ss1, *sums2, *ss2;
    if (big) {
        agg  = (float*)(ws + AGG_OFF);
        xf   = (float*)(ws + XF_OFF);
        hmid = (float*)(ws + HMID_OFF);
        xagg = (float*)(ws + XAGG_OFF);
        aggg = (float*)(ws + AGGG_OFF);
        tbuf = (float*)(ws + TBUF_OFF);
        ubuf = (float*)(ws + UBUF_OFF);
        sums1 = (float*)(ws + STATS_OFF);
    } else {
        agg  = (float*)(ws + S_AGG_OFF);
        xf   = (float*)(ws + S_XF_OFF);
        hmid = (float*)(ws + S_HMID_OFF);
        xagg = (float*)(ws + S_XAGG_OFF);
        aggg = (float*)(ws + S_AGGG_OFF);
        tbuf = (float*)(ws + S_TBUF_OFF);
        ubuf = (float*)(ws + S_UBUF_OFF);
        sums1 = (float*)(ws + S_STATS_OFF);
    }
    ss1   = sums1 + 512;
    sums2 = sums1 + 1024;
    ss2   = sums1 + 1536;
    float* gout = aggg;

    hipMemsetAsync(aggg, 0, (size_t)NGRAPH * HIDDEN * 4, stream);
    hipMemsetAsync(sums1, 0, 8192, stream);

    // GIN pooling (reads x only)
    seg_max_k<<<NGRAPH, 256, 0, stream>>>(x, xagg);

    // CFConv: xf = x @ cf_lin1
    gemm128<0><<<dim3(782, 1), 256, 0, stream>>>(x, cf_lin1, xf, NCONF, NF, HIDDEN,
                                                 nullptr, nullptr, nullptr, nullptr);

    if (big) {
        ushort* Wbuf  = (ushort*)(ws + WBUF_OFF);
        int* deg      = (int*)(ws + DEG_OFF);
        int* startx   = (int*)(ws + START_OFF);
        int* cursor   = (int*)(ws + CURS_OFF);
        int* bsum     = (int*)(ws + BSUM_OFF);
        int* ssrc     = (int*)(ws + SSRC_OFF);
        int* seid     = (int*)(ws + SEID_OFF);

        hipMemsetAsync(deg, 0, 400000, stream);
        hipMemsetAsync(cursor, 0, 400000, stream);

        // CSR by dst
        hist_k<<<(ECONF + 255) / 256, 256, 0, stream>>>(eic, deg);
        scanA_k<<<NBLK, 256, 0, stream>>>(deg, startx, bsum);
        scanB_k<<<1, 512, 0, stream>>>(bsum);
        scanC_k<<<NBLK, 256, 0, stream>>>(startx, bsum);
        fill_csr_k<<<(ECONF + 255) / 256, 256, 0, stream>>>(eic, startx, cursor, ssrc, seid);

        // filter MLP -> bf16 W (cutoff folded)
        edge_mlp_k<<<ECONF / 64, 256, 0, stream>>>(eac, mlp_w1, mlp_b1, mlp_w2, mlp_b2,
                                                   ewc, Wbuf);
        // deterministic gather (replaces 128M f32 atomics)
        gather_k<<<NCONF / 2, 256, 0, stream>>>(startx, deg, seid, ssrc,
                                                (const __hip_bfloat16*)Wbuf, xf, agg);
    } else {
        hipMemsetAsync(agg, 0, (size_t)NCONF * NF * 4, stream);
        edge_mlp_scatter<<<ECONF / 64, 256, 0, stream>>>(eac, mlp_w1, mlp_b1, mlp_w2,
                                                         mlp_b2, ewc, eic, xf, agg);
    }

    // hmid = relu(agg @ cf_lin2 + b)
    gemm128<1><<<dim3(782, 2), 256, 0, stream>>>(agg, cf_lin2, hmid, NCONF, HIDDEN, NF,
                                                 cf_lin2b, nullptr, nullptr, nullptr);

    // GIN branch
    gin_edge_k<<<EGRAPH, 256, 0, stream>>>(xagg, bond_emb, eig, eag, aggg);
    gin_t_k<<<NGRAPH * HIDDEN / 4 / 256, 256, 0, stream>>>(xagg, aggg, gin_eps, tbuf);
    gemm128<0><<<dim3(79, 2), 256, 0, stream>>>(tbuf, gin_w1, ubuf, NGRAPH, HIDDEN, HIDDEN,
                                                gin_b1, nullptr, nullptr, nullptr);
    bn_stats_k<<<(NGRAPH + 255) / 256, 256, 0, stream>>>(ubuf, NGRAPH, sums1);
    bn_final_k<<<1, 256, 0, stream>>>(sums1, bn1_g, bn1_b, NGRAPH, ss1);
    bn_apply_k<true><<<NGRAPH * HIDDEN / 4 / 256, 256, 0, stream>>>(ubuf, ss1, tbuf);
    gemm128<0><<<dim3(79, 2), 256, 0, stream>>>(tbuf, gin_w2, ubuf, NGRAPH, HIDDEN, HIDDEN,
                                                gin_b2, nullptr, nullptr, nullptr);
    bn_stats_k<<<(NGRAPH + 255) / 256, 256, 0, stream>>>(ubuf, NGRAPH, sums2);
    bn_final_k<<<1, 256, 0, stream>>>(sums2, bn2_g, bn2_b, NGRAPH, ss2);
    bn_apply_k<false><<<NGRAPH * HIDDEN / 4 / 256, 256, 0, stream>>>(ubuf, ss2, gout);

    // final: out = x + hmid @ lin_w + lin_b + gout[batch]
    gemm128<2><<<dim3(782, 2), 256, 0, stream>>>(hmid, lin_w, out, NCONF, HIDDEN, HIDDEN,
                                                 lin_b, x, gout, cnb);
}

// Round 4
// 1597.109 us; speedup vs baseline: 2.9619x; 1.2883x over previous
//
#include <hip/hip_runtime.h>
#include <hip/hip_bf16.h>
#include <math.h>

#define HIDDEN 256
#define NG 50
#define NF 128
#define NCONF 100000
#define NGRAPH 10000
#define ECONF 1000000
#define EGRAPH 30000
#define PI_OVER_CUTOFF 0.3141592653589793f
#define NBLK 391                 // ceil(NCONF/256) for scan

typedef __attribute__((ext_vector_type(8))) short bf16x8;
typedef __attribute__((ext_vector_type(4))) float f32x4;

// ---------------- BIG workspace layout (bytes) ----------------
#define AGG_OFF    0ULL            // 100000*128*4 = 51,200,000 (w1p/w2p stashed here pre-gather)
#define XF_OFF     51200000ULL     // 100000*128*4
#define WBUF_OFF   102400000ULL    // 1M*128*2 bf16 = 256,000,000 (dead after gather)
#define HMID_OFF   102400000ULL    // 100000*256*4 overlays dead WBUF
#define XAGG_OFF   358400000ULL
#define AGGG_OFF   368640000ULL
#define TBUF_OFF   378880000ULL
#define UBUF_OFF   389120000ULL
#define STATS_OFF  399360000ULL    // 8192
#define DEG_OFF    399368192ULL    // 400000
#define START_OFF  399768192ULL    // 400000
#define CURS_OFF   400168192ULL    // 400000
#define BSUM_OFF   400568192ULL    // 2048
#define SSRC_OFF   400570240ULL    // 4,000,000
#define SEID_OFF   404570240ULL    // 4,000,000
#define WS_NEEDED  408570240ULL

// ---------------- SMALL (fallback) layout = round-1 ----------------
#define S_AGG_OFF   0ULL
#define S_XF_OFF    51200000ULL
#define S_HMID_OFF  51200000ULL
#define S_XAGG_OFF  153600000ULL
#define S_AGGG_OFF  163840000ULL
#define S_TBUF_OFF  174080000ULL
#define S_UBUF_OFF  184320000ULL
#define S_STATS_OFF 194560000ULL

// ================= generic fp32 GEMM, 128x128 tile, BK=16, 8x8 micro ==========
template<int EPI>
__global__ __launch_bounds__(256) void gemm128(
    const float* __restrict__ A, const float* __restrict__ B,
    float* __restrict__ C, int M, int N, int K,
    const float* __restrict__ bias,
    const float* __restrict__ xres, const float* __restrict__ gin,
    const int* __restrict__ batch)
{
    __shared__ float As[16][132];
    __shared__ float Bs[16][132];
    const int bm = blockIdx.x * 128;
    const int bn = blockIdx.y * 128;
    const int tid = threadIdx.x;
    const int ty = tid >> 4;
    const int tx = tid & 15;
    float acc[8][8];
#pragma unroll
    for (int i = 0; i < 8; ++i)
#pragma unroll
        for (int j = 0; j < 8; ++j) acc[i][j] = 0.f;

    for (int k0 = 0; k0 < K; k0 += 16) {
#pragma unroll
        for (int i = 0; i < 2; ++i) {
            int f = tid + i * 256;
            int row = f >> 2;
            int c4 = (f & 3) << 2;
            int gr = bm + row;
            float4 v = make_float4(0.f, 0.f, 0.f, 0.f);
            if (gr < M) v = *(const float4*)(A + (size_t)gr * K + k0 + c4);
            As[c4 + 0][row] = v.x;
            As[c4 + 1][row] = v.y;
            As[c4 + 2][row] = v.z;
            As[c4 + 3][row] = v.w;
        }
#pragma unroll
        for (int i = 0; i < 2; ++i) {
            int f = tid + i * 256;
            int row = f >> 5;
            int c4 = (f & 31) << 2;
            *(float4*)&Bs[row][c4] = *(const float4*)(B + (size_t)(k0 + row) * N + bn + c4);
        }
        __syncthreads();
#pragma unroll
        for (int k = 0; k < 16; ++k) {
            float a[8], b[8];
            *(float4*)&a[0] = *(const float4*)&As[k][ty * 8];
            *(float4*)&a[4] = *(const float4*)&As[k][ty * 8 + 4];
            *(float4*)&b[0] = *(const float4*)&Bs[k][tx * 8];
            *(float4*)&b[4] = *(const float4*)&Bs[k][tx * 8 + 4];
#pragma unroll
            for (int i = 0; i < 8; ++i)
#pragma unroll
                for (int j = 0; j < 8; ++j)
                    acc[i][j] = fmaf(a[i], b[j], acc[i][j]);
        }
        __syncthreads();
    }

#pragma unroll
    for (int i = 0; i < 8; ++i) {
        int gr = bm + ty * 8 + i;
        if (gr >= M) continue;
        int gb = 0;
        if (EPI == 2) gb = batch[gr];
#pragma unroll
        for (int jj = 0; jj < 2; ++jj) {
            int c0 = bn + tx * 8 + jj * 4;
            float o[4];
#pragma unroll
            for (int q = 0; q < 4; ++q) o[q] = acc[i][jj * 4 + q];
            if (bias != nullptr) {
                float4 bv = *(const float4*)(bias + c0);
                o[0] += bv.x; o[1] += bv.y; o[2] += bv.z; o[3] += bv.w;
            }
            if (EPI == 1) {
#pragma unroll
                for (int q = 0; q < 4; ++q) o[q] = fmaxf(o[q], 0.f);
            }
            if (EPI == 2) {
                float4 xv = *(const float4*)(xres + (size_t)gr * N + c0);
                float4 gv = *(const float4*)(gin + (size_t)gb * N + c0);
                o[0] += xv.x + gv.x; o[1] += xv.y + gv.y;
                o[2] += xv.z + gv.z; o[3] += xv.w + gv.w;
            }
            *(float4*)(C + (size_t)gr * N + c0) = make_float4(o[0], o[1], o[2], o[3]);
        }
    }
}

// ===================== CSR build =====================
__global__ __launch_bounds__(256) void hist_k(const int* __restrict__ ei,
                                              int* __restrict__ deg)
{
    int e = blockIdx.x * 256 + threadIdx.x;
    if (e < ECONF) atomicAdd(&deg[ei[ECONF + e]], 1);
}

__global__ __launch_bounds__(256) void scanA_k(const int* __restrict__ deg,
                                               int* __restrict__ excl,
                                               int* __restrict__ bsum)
{
    __shared__ int s[256];
    int tid = threadIdx.x;
    int i = blockIdx.x * 256 + tid;
    int v = (i < NCONF) ? deg[i] : 0;
    s[tid] = v;
    __syncthreads();
#pragma unroll
    for (int off = 1; off < 256; off <<= 1) {
        int t = (tid >= off) ? s[tid - off] : 0;
        __syncthreads();
        s[tid] += t;
        __syncthreads();
    }
    if (i < NCONF) excl[i] = s[tid] - v;
    if (tid == 255) bsum[blockIdx.x] = s[255];
}

__global__ __launch_bounds__(512) void scanB_k(int* __restrict__ bsum)
{
    __shared__ int s[512];
    int tid = threadIdx.x;
    int v = (tid < NBLK) ? bsum[tid] : 0;
    s[tid] = v;
    __syncthreads();
#pragma unroll
    for (int off = 1; off < 512; off <<= 1) {
        int t = (tid >= off) ? s[tid - off] : 0;
        __syncthreads();
        s[tid] += t;
        __syncthreads();
    }
    if (tid < NBLK) bsum[tid] = s[tid] - v;   // exclusive block offsets, in place
}

__global__ __launch_bounds__(256) void scanC_k(int* __restrict__ excl,
                                               const int* __restrict__ bsum)
{
    int i = blockIdx.x * 256 + threadIdx.x;
    if (i < NCONF) excl[i] += bsum[blockIdx.x];
}

__global__ __launch_bounds__(256) void fill_csr_k(const int* __restrict__ ei,
                                                  const int* __restrict__ startx,
                                                  int* __restrict__ cursor,
                                                  int* __restrict__ ssrc,
                                                  int* __restrict__ seid)
{
    int e = blockIdx.x * 256 + threadIdx.x;
    if (e >= ECONF) return;
    int src = ei[e];
    int dst = ei[ECONF + e];
    int pos = atomicAdd(&cursor[dst], 1);
    int slot = startx[dst] + pos;
    ssrc[slot] = src;
    seid[slot] = e;
}

// ========== weight prep: pack w1/w2 into MFMA B-fragment order, bf16 ==========
// w1p[(ct*2+ks)*64 + lane][j] = bf16(w1[k][n]), n = ct*16+(l&15), k = ks*32+(l>>4)*8+j
// (k >= 50 zero-padded). w2p analogous with 4 k-steps.
__global__ __launch_bounds__(256) void prep_w_k(const float* __restrict__ w1,
                                                const float* __restrict__ w2,
                                                ushort* __restrict__ w1p,
                                                ushort* __restrict__ w2p)
{
    int t = blockIdx.x * 256 + threadIdx.x;
    if (t < 1024) {                       // w1p: 16 chunks * 64 lanes
        int l = t & 63;
        int cks = t >> 6;                 // ct*2+ks
        int n = (cks >> 1) * 16 + (l & 15);
        int ks = cks & 1;
        ushort out[8];
#pragma unroll
        for (int j = 0; j < 8; ++j) {
            int k = ks * 32 + (l >> 4) * 8 + j;
            float v = (k < NG) ? w1[k * NF + n] : 0.f;
            __hip_bfloat16 h = __float2bfloat16(v);
            out[j] = *(ushort*)&h;
        }
        *(uint4*)(w1p + t * 8) = *(uint4*)out;
    } else if (t < 1024 + 2048) {         // w2p: 32 chunks * 64 lanes
        int u = t - 1024;
        int l = u & 63;
        int cks = u >> 6;                 // ct*4+ks
        int n = (cks >> 2) * 16 + (l & 15);
        int ks = cks & 3;
        ushort out[8];
#pragma unroll
        for (int j = 0; j < 8; ++j) {
            int k = ks * 32 + (l >> 4) * 8 + j;
            float v = w2[k * NF + n];
            __hip_bfloat16 h = __float2bfloat16(v);
            out[j] = *(ushort*)&h;
        }
        *(uint4*)(w2p + u * 8) = *(uint4*)out;
    }
}

// ============ MFMA edge MLP -> bf16 W buffer (cutoff folded in) ==============
// 64 edges/block, 4 waves; wave w owns rows [w*16, w*16+16) x all 128 cols.
__global__ __launch_bounds__(256) void edge_mlp_mfma_k(
    const float* __restrict__ EA, const ushort* __restrict__ w1p,
    const float* __restrict__ b1, const ushort* __restrict__ w2p,
    const float* __restrict__ b2, const float* __restrict__ ew,
    ushort* __restrict__ Wout)
{
    __shared__ ushort ea_lds[64 * 64];    // 8 KB  [row][k], XOR-swizzled
    __shared__ ushort t_lds[64 * 128];    // 16 KB [row][k], XOR-swizzled
    __shared__ float ccs[64];

    const int tid = threadIdx.x;
    const int e0 = blockIdx.x * 64;

    // ---- stage EA fp32 -> bf16 LDS (k padded 50->64 with zeros) ----
    {
        int row = tid >> 2, q = tid & 3;
        const float* rp = EA + (size_t)(e0 + row) * NG;
        char* base = (char*)ea_lds + row * 128;
        int swz = (row & 7) << 4;
#pragma unroll
        for (int p = 0; p < 8; ++p) {
            int k = q * 16 + p * 2;
            float2 v = make_float2(0.f, 0.f);
            if (k < NG) v = *(const float2*)(rp + k);   // pair (48,49) fully real
            __hip_bfloat16 h0 = __float2bfloat16(v.x);
            __hip_bfloat16 h1 = __float2bfloat16(v.y);
            uint pk = (uint)(*(ushort*)&h0) | ((uint)(*(ushort*)&h1) << 16);
            *(uint*)(base + ((k * 2) ^ swz)) = pk;
        }
    }
    if (tid < 64)
        ccs[tid] = 0.5f * (cosf(ew[e0 + tid] * PI_OVER_CUTOFF) + 1.0f);
    __syncthreads();

    const int wv = tid >> 6;              // row-tile
    const int l = tid & 63;
    const int l15 = l & 15, lhi = l >> 4;
    const int arow = wv * 16 + l15;
    const int aswz = (arow & 7) << 4;

    // ---- layer 1: T = relu(EA @ w1 + b1), K=64 (2 k-steps) ----
    bf16x8 a1[2];
    {
        const char* eab = (const char*)ea_lds + arow * 128;
        a1[0] = *(const bf16x8*)(eab + ((0 + lhi * 16) ^ aswz));
        a1[1] = *(const bf16x8*)(eab + ((64 + lhi * 16) ^ aswz));
    }
    f32x4 acc1[8];
#pragma unroll
    for (int ct = 0; ct < 8; ++ct) {
        float bb = b1[ct * 16 + l15];
        acc1[ct][0] = bb; acc1[ct][1] = bb; acc1[ct][2] = bb; acc1[ct][3] = bb;
    }
#pragma unroll
    for (int ct = 0; ct < 8; ++ct) {
#pragma unroll
        for (int ks = 0; ks < 2; ++ks) {
            bf16x8 bfr = *(const bf16x8*)(w1p + ((size_t)(ct * 2 + ks) * 64 + l) * 8);
            acc1[ct] = __builtin_amdgcn_mfma_f32_16x16x32_bf16(a1[ks], bfr, acc1[ct], 0, 0, 0);
        }
    }
    // relu -> t_lds (C layout: col=l&15, row=lhi*4+q)
#pragma unroll
    for (int ct = 0; ct < 8; ++ct) {
#pragma unroll
        for (int q = 0; q < 4; ++q) {
            int row = wv * 16 + lhi * 4 + q;
            int col = ct * 16 + l15;
            float v = fmaxf(acc1[ct][q], 0.f);
            __hip_bfloat16 h = __float2bfloat16(v);
            *(ushort*)((char*)t_lds + ((row * 256 + col * 2) ^ ((row & 7) << 4))) = *(ushort*)&h;
        }
    }
    __syncthreads();

    // ---- layer 2: W = T @ w2 + b2, K=128 (4 k-steps) ----
    bf16x8 a2[4];
    {
        const char* tb = (const char*)t_lds + arow * 256;
#pragma unroll
        for (int ks = 0; ks < 4; ++ks)
            a2[ks] = *(const bf16x8*)(tb + ((ks * 64 + lhi * 16) ^ aswz));
    }
    f32x4 acc2[8];
#pragma unroll
    for (int ct = 0; ct < 8; ++ct) {
        float bb = b2[ct * 16 + l15];
        acc2[ct][0] = bb; acc2[ct][1] = bb; acc2[ct][2] = bb; acc2[ct][3] = bb;
    }
#pragma unroll
    for (int ct = 0; ct < 8; ++ct) {
#pragma unroll
        for (int ks = 0; ks < 4; ++ks) {
            bf16x8 bfr = *(const bf16x8*)(w2p + ((size_t)(ct * 4 + ks) * 64 + l) * 8);
            acc2[ct] = __builtin_amdgcn_mfma_f32_16x16x32_bf16(a2[ks], bfr, acc2[ct], 0, 0, 0);
        }
    }

    // ---- epilogue: scale by cosine cutoff, store bf16 ----
    float ccr[4];
#pragma unroll
    for (int q = 0; q < 4; ++q) ccr[q] = ccs[wv * 16 + lhi * 4 + q];
#pragma unroll
    for (int ct = 0; ct < 8; ++ct) {
#pragma unroll
        for (int q = 0; q < 4; ++q) {
            int row = wv * 16 + lhi * 4 + q;
            int col = ct * 16 + l15;
            __hip_bfloat16 h = __float2bfloat16(acc2[ct][q] * ccr[q]);
            Wout[(size_t)(e0 + row) * NF + col] = *(ushort*)&h;
        }
    }
}

// ============ deterministic gather: agg[d] = sum_e W[e] * xf[src[e]] ============
__global__ __launch_bounds__(256) void gather_k(
    const int* __restrict__ startx, const int* __restrict__ deg,
    const int* __restrict__ seid, const int* __restrict__ ssrc,
    const __hip_bfloat16* __restrict__ Wbuf, const float* __restrict__ xf,
    float* __restrict__ agg)
{
    int d = blockIdx.x * 2 + (threadIdx.x >> 7);
    int c = threadIdx.x & 127;
    int s0 = startx[d];
    int n = deg[d];
    float acc = 0.f;
    for (int i = 0; i < n; ++i) {
        int e = seid[s0 + i];
        int src = ssrc[s0 + i];
        float w = __bfloat162float(Wbuf[(size_t)e * NF + c]);
        acc = fmaf(w, xf[(size_t)src * NF + c], acc);
    }
    agg[(size_t)d * NF + c] = acc;
}

// ============ fallback: round-1 fused atomic kernel (small ws only) ==========
__global__ __launch_bounds__(256) void edge_mlp_scatter(
    const float* __restrict__ EA, const float* __restrict__ w1,
    const float* __restrict__ b1, const float* __restrict__ w2,
    const float* __restrict__ b2, const float* __restrict__ ew,
    const int* __restrict__ ei, const float* __restrict__ xf,
    float* __restrict__ agg)
{
    __shared__ float w1s[NG * NF];
    __shared__ float b1s[NF];
    __shared__ float w2s[NF * NF];
    __shared__ float b2s[NF];
    __shared__ float eas[64 * NG];
    __shared__ float ts[64 * 132];

    const int tid = threadIdx.x;
    for (int i = tid; i < NG * NF / 4; i += 256)
        ((float4*)w1s)[i] = ((const float4*)w1)[i];
    for (int i = tid; i < NF * NF / 4; i += 256)
        ((float4*)w2s)[i] = ((const float4*)w2)[i];
    if (tid < NF / 4) ((float4*)b1s)[tid] = ((const float4*)b1)[tid];
    else if (tid < NF / 2) ((float4*)b2s)[tid - NF / 4] = ((const float4*)b2)[tid - NF / 4];

    const int e0 = blockIdx.x * 64;
    for (int i = tid; i < 64 * NG / 4; i += 256)
        ((float4*)eas)[i] = ((const float4*)(EA + (size_t)e0 * NG))[i];
    __syncthreads();

    const int tr = tid >> 4;
    const int tc = tid & 15;

    float acc[4][8];
#pragma unroll
    for (int i = 0; i < 4; ++i)
#pragma unroll
        for (int j = 0; j < 8; ++j) acc[i][j] = b1s[tc * 8 + j];
    for (int k = 0; k < NG; ++k) {
        float b[8];
        *(float4*)&b[0] = *(const float4*)&w1s[k * NF + tc * 8];
        *(float4*)&b[4] = *(const float4*)&w1s[k * NF + tc * 8 + 4];
#pragma unroll
        for (int i = 0; i < 4; ++i) {
            float a = eas[(tr * 4 + i) * NG + k];
#pragma unroll
            for (int j = 0; j < 8; ++j) acc[i][j] = fmaf(a, b[j], acc[i][j]);
        }
    }
#pragma unroll
    for (int i = 0; i < 4; ++i)
#pragma unroll
        for (int jj = 0; jj < 2; ++jj) {
            float4 v;
            v.x = fmaxf(acc[i][jj * 4 + 0], 0.f);
            v.y = fmaxf(acc[i][jj * 4 + 1], 0.f);
            v.z = fmaxf(acc[i][jj * 4 + 2], 0.f);
            v.w = fmaxf(acc[i][jj * 4 + 3], 0.f);
            *(float4*)&ts[(tr * 4 + i) * 132 + tc * 8 + jj * 4] = v;
        }
    __syncthreads();

    float acc2[4][8];
#pragma unroll
    for (int i = 0; i < 4; ++i)
#pragma unroll
        for (int j = 0; j < 8; ++j) acc2[i][j] = b2s[tc * 8 + j];
    for (int k = 0; k < NF; ++k) {
        float b[8];
        *(float4*)&b[0] = *(const float4*)&w2s[k * NF + tc * 8];
        *(float4*)&b[4] = *(const float4*)&w2s[k * NF + tc * 8 + 4];
#pragma unroll
        for (int i = 0; i < 4; ++i) {
            float a = ts[(tr * 4 + i) * 132 + k];
#pragma unroll
            for (int j = 0; j < 8; ++j) acc2[i][j] = fmaf(a, b[j], acc2[i][j]);
        }
    }

#pragma unroll
    for (int i = 0; i < 4; ++i) {
        int e = e0 + tr * 4 + i;
        int src = ei[e];
        int dst = ei[ECONF + e];
        float cc = 0.5f * (cosf(ew[e] * PI_OVER_CUTOFF) + 1.0f);
        float4 x0 = *(const float4*)(xf + (size_t)src * NF + tc * 8);
        float4 x1 = *(const float4*)(xf + (size_t)src * NF + tc * 8 + 4);
        float xv[8] = { x0.x, x0.y, x0.z, x0.w, x1.x, x1.y, x1.z, x1.w };
        float* ap = agg + (size_t)dst * NF + tc * 8;
#pragma unroll
        for (int j = 0; j < 8; ++j)
            atomicAdd(ap + j, cc * acc2[i][j] * xv[j]);
    }
}

// ================= small kernels =================
__global__ __launch_bounds__(256) void seg_max_k(const float* __restrict__ x,
                                                 float* __restrict__ xagg)
{
    int g = blockIdx.x;
    int c = threadIdx.x;
    float m = -INFINITY;
#pragma unroll
    for (int r = 0; r < NCONF / NGRAPH; ++r)
        m = fmaxf(m, x[((size_t)g * (NCONF / NGRAPH) + r) * HIDDEN + c]);
    xagg[(size_t)g * HIDDEN + c] = m;
}

__global__ __launch_bounds__(256) void gin_edge_k(const float* __restrict__ xagg,
                                                  const float* __restrict__ bemb,
                                                  const int* __restrict__ eig,
                                                  const int* __restrict__ eag,
                                                  float* __restrict__ aggg)
{
    int e = blockIdx.x;
    int c = threadIdx.x;
    int sg = eig[e];
    int dg = eig[EGRAPH + e];
    int f0 = eag[e * 3 + 0];
    int f1 = eag[e * 3 + 1];
    int f2 = eag[e * 3 + 2];
    float v = xagg[(size_t)sg * HIDDEN + c]
            + bemb[(0 * 5 + f0) * HIDDEN + c]
            + bemb[(1 * 5 + f1) * HIDDEN + c]
            + bemb[(2 * 5 + f2) * HIDDEN + c];
    v = fmaxf(v, 0.f);
    atomicAdd(&aggg[(size_t)dg * HIDDEN + c], v);
}

__global__ __launch_bounds__(256) void gin_t_k(const float* __restrict__ xagg,
                                               const float* __restrict__ aggg,
                                               const float* __restrict__ epsp,
                                               float* __restrict__ t)
{
    int idx = blockIdx.x * 256 + threadIdx.x;
    float e1 = 1.f + epsp[0];
    float4 a = ((const float4*)xagg)[idx];
    float4 g = ((const float4*)aggg)[idx];
    ((float4*)t)[idx] = make_float4(e1 * a.x + g.x, e1 * a.y + g.y,
                                    e1 * a.z + g.z, e1 * a.w + g.w);
}

__global__ __launch_bounds__(256) void bn_stats_k(const float* __restrict__ u, int M,
                                                  float* __restrict__ sums)
{
    int c = threadIdx.x;
    int r0 = blockIdx.x * 256;
    int rend = min(r0 + 256, M);
    float s = 0.f, s2 = 0.f;
    for (int r = r0; r < rend; ++r) {
        float v = u[(size_t)r * HIDDEN + c];
        s += v;
        s2 = fmaf(v, v, s2);
    }
    atomicAdd(&sums[c], s);
    atomicAdd(&sums[HIDDEN + c], s2);
}

__global__ __launch_bounds__(256) void bn_final_k(const float* __restrict__ sums,
                                                  const float* __restrict__ g,
                                                  const float* __restrict__ b,
                                                  int M, float* __restrict__ ss)
{
    int c = threadIdx.x;
    float mean = sums[c] / (float)M;
    float var = sums[HIDDEN + c] / (float)M - mean * mean;
    float sc = g[c] / sqrtf(var + 1e-5f);
    ss[c] = sc;
    ss[HIDDEN + c] = b[c] - mean * sc;
}

template<bool RELU>
__global__ __launch_bounds__(256) void bn_apply_k(const float* __restrict__ u,
                                                  const float* __restrict__ ss,
                                                  float* __restrict__ out)
{
    int idx = blockIdx.x * 256 + threadIdx.x;
    int c4 = (idx & (HIDDEN / 4 - 1)) * 4;
    float4 v = ((const float4*)u)[idx];
    float4 sc = *(const float4*)&ss[c4];
    float4 sh = *(const float4*)&ss[HIDDEN + c4];
    float4 o = make_float4(v.x * sc.x + sh.x, v.y * sc.y + sh.y,
                           v.z * sc.z + sh.z, v.w * sc.w + sh.w);
    if (RELU) {
        o.x = fmaxf(o.x, 0.f); o.y = fmaxf(o.y, 0.f);
        o.z = fmaxf(o.z, 0.f); o.w = fmaxf(o.w, 0.f);
    }
    ((float4*)out)[idx] = o;
}

// ================= launch =================
extern "C" void kernel_launch(void* const* d_in, const int* in_sizes, int n_in,
                              void* d_out, int out_size, void* d_ws, size_t ws_size,
                              hipStream_t stream)
{
    const float* x        = (const float*)d_in[0];
    const int*   cnb      = (const int*)d_in[1];
    const int*   eic      = (const int*)d_in[2];
    const float* ewc      = (const float*)d_in[3];
    const float* eac      = (const float*)d_in[4];
    const int*   eig      = (const int*)d_in[5];
    const int*   eag      = (const int*)d_in[6];
    const float* mlp_w1   = (const float*)d_in[7];
    const float* mlp_b1   = (const float*)d_in[8];
    const float* mlp_w2   = (const float*)d_in[9];
    const float* mlp_b2   = (const float*)d_in[10];
    const float* cf_lin1  = (const float*)d_in[11];
    const float* cf_lin2  = (const float*)d_in[12];
    const float* cf_lin2b = (const float*)d_in[13];
    const float* lin_w    = (const float*)d_in[14];
    const float* lin_b    = (const float*)d_in[15];
    const float* bond_emb = (const float*)d_in[16];
    const float* gin_eps  = (const float*)d_in[17];
    const float* gin_w1   = (const float*)d_in[18];
    const float* gin_b1   = (const float*)d_in[19];
    const float* bn1_g    = (const float*)d_in[20];
    const float* bn1_b    = (const float*)d_in[21];
    const float* gin_w2   = (const float*)d_in[22];
    const float* gin_b2   = (const float*)d_in[23];
    const float* bn2_g    = (const float*)d_in[24];
    const float* bn2_b    = (const float*)d_in[25];
    float* out = (float*)d_out;

    char* ws = (char*)d_ws;
    const bool big = (ws_size >= WS_NEEDED);

    float* agg, *xf, *hmid, *xagg, *aggg, *tbuf, *ubuf, *sums1, *ss1, *sums2, *ss2;
    if (big) {
        agg  = (float*)(ws + AGG_OFF);
        xf   = (float*)(ws + XF_OFF);
        hmid = (float*)(ws + HMID_OFF);
        xagg = (float*)(ws + XAGG_OFF);
        aggg = (float*)(ws + AGGG_OFF);
        tbuf = (float*)(ws + TBUF_OFF);
        ubuf = (float*)(ws + UBUF_OFF);
        sums1 = (float*)(ws + STATS_OFF);
    } else {
        agg  = (float*)(ws + S_AGG_OFF);
        xf   = (float*)(ws + S_XF_OFF);
        hmid = (float*)(ws + S_HMID_OFF);
        xagg = (float*)(ws + S_XAGG_OFF);
        aggg = (float*)(ws + S_AGGG_OFF);
        tbuf = (float*)(ws + S_TBUF_OFF);
        ubuf = (float*)(ws + S_UBUF_OFF);
        sums1 = (float*)(ws + S_STATS_OFF);
    }
    ss1   = sums1 + 512;
    sums2 = sums1 + 1024;
    ss2   = sums1 + 1536;
    float* gout = aggg;

    hipMemsetAsync(aggg, 0, (size_t)NGRAPH * HIDDEN * 4, stream);
    hipMemsetAsync(sums1, 0, 8192, stream);

    // GIN pooling (reads x only)
    seg_max_k<<<NGRAPH, 256, 0, stream>>>(x, xagg);

    // CFConv: xf = x @ cf_lin1
    gemm128<0><<<dim3(782, 1), 256, 0, stream>>>(x, cf_lin1, xf, NCONF, NF, HIDDEN,
                                                 nullptr, nullptr, nullptr, nullptr);

    if (big) {
        ushort* Wbuf  = (ushort*)(ws + WBUF_OFF);
        int* deg      = (int*)(ws + DEG_OFF);
        int* startx   = (int*)(ws + START_OFF);
        int* cursor   = (int*)(ws + CURS_OFF);
        int* bsum     = (int*)(ws + BSUM_OFF);
        int* ssrc     = (int*)(ws + SSRC_OFF);
        int* seid     = (int*)(ws + SEID_OFF);
        // stash packed weights in agg region (dead until gather_k rewrites it)
        ushort* w1p   = (ushort*)(ws + AGG_OFF);
        ushort* w2p   = (ushort*)(ws + AGG_OFF + 16384);

        hipMemsetAsync(deg, 0, 400000, stream);
        hipMemsetAsync(cursor, 0, 400000, stream);

        // pack weights into MFMA fragment order
        prep_w_k<<<12, 256, 0, stream>>>(mlp_w1, mlp_w2, w1p, w2p);

        // CSR by dst
        hist_k<<<(ECONF + 255) / 256, 256, 0, stream>>>(eic, deg);
        scanA_k<<<NBLK, 256, 0, stream>>>(deg, startx, bsum);
        scanB_k<<<1, 512, 0, stream>>>(bsum);
        scanC_k<<<NBLK, 256, 0, stream>>>(startx, bsum);
        fill_csr_k<<<(ECONF + 255) / 256, 256, 0, stream>>>(eic, startx, cursor, ssrc, seid);

        // MFMA filter MLP -> bf16 W (cutoff folded)
        edge_mlp_mfma_k<<<ECONF / 64, 256, 0, stream>>>(eac, w1p, mlp_b1, w2p, mlp_b2,
                                                        ewc, Wbuf);
        // deterministic gather (overwrites w1p/w2p region with agg)
        gather_k<<<NCONF / 2, 256, 0, stream>>>(startx, deg, seid, ssrc,
                                                (const __hip_bfloat16*)Wbuf, xf, agg);
    } else {
        hipMemsetAsync(agg, 0, (size_t)NCONF * NF * 4, stream);
        edge_mlp_scatter<<<ECONF / 64, 256, 0, stream>>>(eac, mlp_w1, mlp_b1, mlp_w2,
                                                         mlp_b2, ewc, eic, xf, agg);
    }

    // hmid = relu(agg @ cf_lin2 + b)
    gemm128<1><<<dim3(782, 2), 256, 0, stream>>>(agg, cf_lin2, hmid, NCONF, HIDDEN, NF,
                                                 cf_lin2b, nullptr, nullptr, nullptr);

    // GIN branch
    gin_edge_k<<<EGRAPH, 256, 0, stream>>>(xagg, bond_emb, eig, eag, aggg);
    gin_t_k<<<NGRAPH * HIDDEN / 4 / 256, 256, 0, stream>>>(xagg, aggg, gin_eps, tbuf);
    gemm128<0><<<dim3(79, 2), 256, 0, stream>>>(tbuf, gin_w1, ubuf, NGRAPH, HIDDEN, HIDDEN,
                                                gin_b1, nullptr, nullptr, nullptr);
    bn_stats_k<<<(NGRAPH + 255) / 256, 256, 0, stream>>>(ubuf, NGRAPH, sums1);
    bn_final_k<<<1, 256, 0, stream>>>(sums1, bn1_g, bn1_b, NGRAPH, ss1);
    bn_apply_k<true><<<NGRAPH * HIDDEN / 4 / 256, 256, 0, stream>>>(ubuf, ss1, tbuf);
    gemm128<0><<<dim3(79, 2), 256, 0, stream>>>(tbuf, gin_w2, ubuf, NGRAPH, HIDDEN, HIDDEN,
                                                gin_b2, nullptr, nullptr, nullptr);
    bn_stats_k<<<(NGRAPH + 255) / 256, 256, 0, stream>>>(ubuf, NGRAPH, sums2);
    bn_final_k<<<1, 256, 0, stream>>>(sums2, bn2_g, bn2_b, NGRAPH, ss2);
    bn_apply_k<false><<<NGRAPH * HIDDEN / 4 / 256, 256, 0, stream>>>(ubuf, ss2, gout);

    // final: out = x + hmid @ lin_w + lin_b + gout[batch]
    gemm128<2><<<dim3(782, 2), 256, 0, stream>>>(hmid, lin_w, out, NCONF, HIDDEN, HIDDEN,
                                                 lin_b, x, gout, cnb);
}

// Round 5
// 1332.191 us; speedup vs baseline: 3.5509x; 1.1989x over previous
//
#include <hip/hip_runtime.h>
#include <hip/hip_bf16.h>
#include <math.h>

#define HIDDEN 256
#define NG 50
#define NF 128
#define NCONF 100000
#define NGRAPH 10000
#define ECONF 1000000
#define EGRAPH 30000
#define PI_OVER_CUTOFF 0.3141592653589793f
#define NBLK 391                 // ceil(NCONF/256) for scan

typedef __attribute__((ext_vector_type(8))) short bf16x8;
typedef __attribute__((ext_vector_type(4))) float f32x4;

__device__ inline ushort f2b(float v) {
    __hip_bfloat16 h = __float2bfloat16(v);
    return *(ushort*)&h;
}
__device__ inline float b2f(ushort u) {
    union { uint i; float f; } c; c.i = (uint)u << 16; return c.f;
}

// ---------------- BIG workspace layout (bytes) ----------------
#define XFB_OFF    0ULL            // 100000*128*2 bf16 = 25,600,000
#define AGGB_OFF   25600000ULL     // 100000*128*2 bf16
#define WBUF_OFF   51200000ULL     // 1M*128*2 bf16 = 256,000,000 (CSR order; dead after gather)
#define HMIDB_OFF  51200000ULL     // 100000*256*2 bf16 overlays dead WBUF
#define XAGG_OFF   307200000ULL
#define AGGG_OFF   317440000ULL
#define TBUF_OFF   327680000ULL
#define UBUF_OFF   337920000ULL
#define STATS_OFF  348160000ULL    // 8192
#define DEG_OFF    348168192ULL    // 400000
#define START_OFF  348568192ULL    // 400000
#define CURS_OFF   348968192ULL    // 400000
#define BSUM_OFF   349368192ULL    // 2048
#define SSRC_OFF   349370240ULL    // 4,000,000
#define SEID_OFF   353370240ULL    // 4,000,000
#define W1P_OFF    357370240ULL    // 16,384
#define W2P_OFF    357386624ULL    // 32,768
#define L1P_OFF    357419392ULL    // 65,536  cf_lin1 packed
#define L2P_OFF    357484928ULL    // 65,536  cf_lin2 packed
#define LWP_OFF    357550464ULL    // 131,072 lin_w packed
#define WS_NEEDED  357681536ULL

// ---------------- SMALL (fallback) layout = round-1 ----------------
#define S_AGG_OFF   0ULL
#define S_XF_OFF    51200000ULL
#define S_HMID_OFF  51200000ULL
#define S_XAGG_OFF  153600000ULL
#define S_AGGG_OFF  163840000ULL
#define S_TBUF_OFF  174080000ULL
#define S_UBUF_OFF  184320000ULL
#define S_STATS_OFF 194560000ULL

// ================= generic fp32 GEMM (GIN branch + fallback) ==========
template<int EPI>
__global__ __launch_bounds__(256) void gemm128(
    const float* __restrict__ A, const float* __restrict__ B,
    float* __restrict__ C, int M, int N, int K,
    const float* __restrict__ bias,
    const float* __restrict__ xres, const float* __restrict__ gin,
    const int* __restrict__ batch)
{
    __shared__ float As[16][132];
    __shared__ float Bs[16][132];
    const int bm = blockIdx.x * 128;
    const int bn = blockIdx.y * 128;
    const int tid = threadIdx.x;
    const int ty = tid >> 4;
    const int tx = tid & 15;
    float acc[8][8];
#pragma unroll
    for (int i = 0; i < 8; ++i)
#pragma unroll
        for (int j = 0; j < 8; ++j) acc[i][j] = 0.f;

    for (int k0 = 0; k0 < K; k0 += 16) {
#pragma unroll
        for (int i = 0; i < 2; ++i) {
            int f = tid + i * 256;
            int row = f >> 2;
            int c4 = (f & 3) << 2;
            int gr = bm + row;
            float4 v = make_float4(0.f, 0.f, 0.f, 0.f);
            if (gr < M) v = *(const float4*)(A + (size_t)gr * K + k0 + c4);
            As[c4 + 0][row] = v.x;
            As[c4 + 1][row] = v.y;
            As[c4 + 2][row] = v.z;
            As[c4 + 3][row] = v.w;
        }
#pragma unroll
        for (int i = 0; i < 2; ++i) {
            int f = tid + i * 256;
            int row = f >> 5;
            int c4 = (f & 31) << 2;
            *(float4*)&Bs[row][c4] = *(const float4*)(B + (size_t)(k0 + row) * N + bn + c4);
        }
        __syncthreads();
#pragma unroll
        for (int k = 0; k < 16; ++k) {
            float a[8], b[8];
            *(float4*)&a[0] = *(const float4*)&As[k][ty * 8];
            *(float4*)&a[4] = *(const float4*)&As[k][ty * 8 + 4];
            *(float4*)&b[0] = *(const float4*)&Bs[k][tx * 8];
            *(float4*)&b[4] = *(const float4*)&Bs[k][tx * 8 + 4];
#pragma unroll
            for (int i = 0; i < 8; ++i)
#pragma unroll
                for (int j = 0; j < 8; ++j)
                    acc[i][j] = fmaf(a[i], b[j], acc[i][j]);
        }
        __syncthreads();
    }

#pragma unroll
    for (int i = 0; i < 8; ++i) {
        int gr = bm + ty * 8 + i;
        if (gr >= M) continue;
        int gb = 0;
        if (EPI == 2) gb = batch[gr];
#pragma unroll
        for (int jj = 0; jj < 2; ++jj) {
            int c0 = bn + tx * 8 + jj * 4;
            float o[4];
#pragma unroll
            for (int q = 0; q < 4; ++q) o[q] = acc[i][jj * 4 + q];
            if (bias != nullptr) {
                float4 bv = *(const float4*)(bias + c0);
                o[0] += bv.x; o[1] += bv.y; o[2] += bv.z; o[3] += bv.w;
            }
            if (EPI == 1) {
#pragma unroll
                for (int q = 0; q < 4; ++q) o[q] = fmaxf(o[q], 0.f);
            }
            if (EPI == 2) {
                float4 xv = *(const float4*)(xres + (size_t)gr * N + c0);
                float4 gv = *(const float4*)(gin + (size_t)gb * N + c0);
                o[0] += xv.x + gv.x; o[1] += xv.y + gv.y;
                o[2] += xv.z + gv.z; o[3] += xv.w + gv.w;
            }
            *(float4*)(C + (size_t)gr * N + c0) = make_float4(o[0], o[1], o[2], o[3]);
        }
    }
}

// ============== generic bf16 MFMA GEMM: 64-row tile, full-N, 4 waves ==========
// A [M x KD] (f32 or bf16), Bp packed [(nt*(KD/32)+ks)*64+lane][8] bf16.
// EPI 0: C=bf16(acc);  1: C=bf16(relu(acc+bias));  2: C=f32(acc+bias+x+gin[batch])
template<int EPI, int KD, int ND, typename AT>
__global__ __launch_bounds__(256) void gemm_mfma(
    const AT* __restrict__ A, const ushort* __restrict__ Bp,
    void* __restrict__ Cv, int M,
    const float* __restrict__ bias,
    const float* __restrict__ xres, const float* __restrict__ gin,
    const int* __restrict__ batch)
{
    __shared__ ushort a_lds[64 * KD];    // XOR-swizzled
    const int tid = threadIdx.x;
    const int bm = blockIdx.x * 64;

    // ---- stage A -> bf16 LDS ----
    {
        int row = tid >> 2, q = tid & 3;
        int gr = bm + row;
        char* base = (char*)a_lds + row * (KD * 2);
        int swz = (row & 7) << 4;
        const AT* rp = A + (size_t)gr * KD;
#pragma unroll
        for (int p = 0; p < KD / 32; ++p) {
            int k = q * (KD / 4) + p * 8;
            uint4 pk = make_uint4(0, 0, 0, 0);
            if (gr < M) {
                if constexpr (sizeof(AT) == 4) {
                    float4 v0 = *(const float4*)(rp + k);
                    float4 v1 = *(const float4*)(rp + k + 4);
                    ushort o[8] = { f2b(v0.x), f2b(v0.y), f2b(v0.z), f2b(v0.w),
                                    f2b(v1.x), f2b(v1.y), f2b(v1.z), f2b(v1.w) };
                    pk = *(uint4*)o;
                } else {
                    pk = *(const uint4*)(rp + k);
                }
            }
            *(uint4*)(base + ((k * 2) ^ swz)) = pk;
        }
    }
    __syncthreads();

    const int wv = tid >> 6, l = tid & 63, l15 = l & 15, lhi = l >> 4;
    const int arow = wv * 16 + l15, aswz = (arow & 7) << 4;

    bf16x8 a[KD / 32];
    const char* ab = (const char*)a_lds + arow * (KD * 2);
#pragma unroll
    for (int ks = 0; ks < KD / 32; ++ks)
        a[ks] = *(const bf16x8*)(ab + ((ks * 64 + lhi * 16) ^ aswz));

    f32x4 acc[ND / 16];
#pragma unroll
    for (int nt = 0; nt < ND / 16; ++nt) {
        float bb = 0.f;
        if constexpr (EPI != 0) bb = bias[nt * 16 + l15];
        acc[nt][0] = bb; acc[nt][1] = bb; acc[nt][2] = bb; acc[nt][3] = bb;
    }
#pragma unroll
    for (int nt = 0; nt < ND / 16; ++nt)
#pragma unroll
        for (int ks = 0; ks < KD / 32; ++ks) {
            bf16x8 bfr = *(const bf16x8*)(Bp + ((size_t)(nt * (KD / 32) + ks) * 64 + l) * 8);
            acc[nt] = __builtin_amdgcn_mfma_f32_16x16x32_bf16(a[ks], bfr, acc[nt], 0, 0, 0);
        }

    int gb[4];
    if constexpr (EPI == 2) {
#pragma unroll
        for (int q = 0; q < 4; ++q) {
            int gr = bm + wv * 16 + lhi * 4 + q;
            gb[q] = (gr < M) ? batch[gr] : 0;
        }
    }
#pragma unroll
    for (int nt = 0; nt < ND / 16; ++nt) {
        int col = nt * 16 + l15;
#pragma unroll
        for (int q = 0; q < 4; ++q) {
            int gr = bm + wv * 16 + lhi * 4 + q;
            if (gr >= M) continue;
            float v = acc[nt][q];
            if constexpr (EPI == 1) v = fmaxf(v, 0.f);
            if constexpr (EPI <= 1) {
                ((ushort*)Cv)[(size_t)gr * ND + col] = f2b(v);
            } else {
                v += xres[(size_t)gr * ND + col] + gin[(size_t)gb[q] * ND + col];
                ((float*)Cv)[(size_t)gr * ND + col] = v;
            }
        }
    }
}

// ===================== CSR build =====================
__global__ __launch_bounds__(256) void hist_k(const int* __restrict__ ei,
                                              int* __restrict__ deg)
{
    int e = blockIdx.x * 256 + threadIdx.x;
    if (e < ECONF) atomicAdd(&deg[ei[ECONF + e]], 1);
}

__global__ __launch_bounds__(256) void scanA_k(const int* __restrict__ deg,
                                               int* __restrict__ excl,
                                               int* __restrict__ bsum)
{
    __shared__ int s[256];
    int tid = threadIdx.x;
    int i = blockIdx.x * 256 + tid;
    int v = (i < NCONF) ? deg[i] : 0;
    s[tid] = v;
    __syncthreads();
#pragma unroll
    for (int off = 1; off < 256; off <<= 1) {
        int t = (tid >= off) ? s[tid - off] : 0;
        __syncthreads();
        s[tid] += t;
        __syncthreads();
    }
    if (i < NCONF) excl[i] = s[tid] - v;
    if (tid == 255) bsum[blockIdx.x] = s[255];
}

__global__ __launch_bounds__(512) void scanB_k(int* __restrict__ bsum)
{
    __shared__ int s[512];
    int tid = threadIdx.x;
    int v = (tid < NBLK) ? bsum[tid] : 0;
    s[tid] = v;
    __syncthreads();
#pragma unroll
    for (int off = 1; off < 512; off <<= 1) {
        int t = (tid >= off) ? s[tid - off] : 0;
        __syncthreads();
        s[tid] += t;
        __syncthreads();
    }
    if (tid < NBLK) bsum[tid] = s[tid] - v;   // exclusive block offsets, in place
}

__global__ __launch_bounds__(256) void scanC_k(int* __restrict__ excl,
                                               const int* __restrict__ bsum)
{
    int i = blockIdx.x * 256 + threadIdx.x;
    if (i < NCONF) excl[i] += bsum[blockIdx.x];
}

__global__ __launch_bounds__(256) void fill_csr_k(const int* __restrict__ ei,
                                                  const int* __restrict__ startx,
                                                  int* __restrict__ cursor,
                                                  int* __restrict__ ssrc,
                                                  int* __restrict__ seid)
{
    int e = blockIdx.x * 256 + threadIdx.x;
    if (e >= ECONF) return;
    int src = ei[e];
    int dst = ei[ECONF + e];
    int pos = atomicAdd(&cursor[dst], 1);
    int slot = startx[dst] + pos;
    ssrc[slot] = src;
    seid[slot] = e;
}

// ========== weight prep: pack into MFMA B-fragment order, bf16 ==========
__global__ __launch_bounds__(256) void prep_w_k(const float* __restrict__ w1,
                                                const float* __restrict__ w2,
                                                ushort* __restrict__ w1p,
                                                ushort* __restrict__ w2p)
{
    int t = blockIdx.x * 256 + threadIdx.x;
    if (t < 1024) {                       // w1p: 16 chunks * 64 lanes (K=50 pad->64)
        int l = t & 63;
        int cks = t >> 6;                 // ct*2+ks
        int n = (cks >> 1) * 16 + (l & 15);
        int ks = cks & 1;
        ushort out[8];
#pragma unroll
        for (int j = 0; j < 8; ++j) {
            int k = ks * 32 + (l >> 4) * 8 + j;
            out[j] = (k < NG) ? f2b(w1[k * NF + n]) : (ushort)0;
        }
        *(uint4*)(w1p + t * 8) = *(uint4*)out;
    } else if (t < 1024 + 2048) {         // w2p: 32 chunks * 64 lanes
        int u = t - 1024;
        int l = u & 63;
        int cks = u >> 6;                 // ct*4+ks
        int n = (cks >> 2) * 16 + (l & 15);
        int ks = cks & 3;
        ushort out[8];
#pragma unroll
        for (int j = 0; j < 8; ++j) {
            int k = ks * 32 + (l >> 4) * 8 + j;
            out[j] = f2b(w2[k * NF + n]);
        }
        *(uint4*)(w2p + u * 8) = *(uint4*)out;
    }
}

// generic K,N pack (K multiple of 32, N multiple of 16)
__global__ __launch_bounds__(256) void prep_pack_k(const float* __restrict__ w,
                                                   ushort* __restrict__ wp,
                                                   int K, int N)
{
    int t = blockIdx.x * 256 + threadIdx.x;
    int total = (N / 16) * (K / 32) * 64;
    if (t >= total) return;
    int l = t & 63;
    int cks = t >> 6;
    int nks = K / 32;
    int nt = cks / nks, ks = cks - nt * nks;
    int n = nt * 16 + (l & 15);
    ushort out[8];
#pragma unroll
    for (int j = 0; j < 8; ++j) {
        int k = ks * 32 + (l >> 4) * 8 + j;
        out[j] = f2b(w[k * N + n]);
    }
    *(uint4*)(wp + t * 8) = *(uint4*)out;
}

// ============ MFMA edge MLP -> bf16 W buffer in CSR slot order ==============
// Block b handles CSR slots [b*64, b*64+64); EA rows gathered via seid.
__global__ __launch_bounds__(256) void edge_mlp_mfma_k(
    const float* __restrict__ EA, const ushort* __restrict__ w1p,
    const float* __restrict__ b1, const ushort* __restrict__ w2p,
    const float* __restrict__ b2, const float* __restrict__ ew,
    const int* __restrict__ seid,
    ushort* __restrict__ Wout)
{
    __shared__ ushort ea_lds[64 * 64];    // 8 KB  [row][k], XOR-swizzled
    __shared__ ushort t_lds[64 * 128];    // 16 KB [row][k], XOR-swizzled
    __shared__ float ccs[64];

    const int tid = threadIdx.x;
    const int e0 = blockIdx.x * 64;

    // ---- stage EA (gathered by seid) fp32 -> bf16 LDS (k padded 50->64) ----
    {
        int row = tid >> 2, q = tid & 3;
        int e = seid[e0 + row];
        const float* rp = EA + (size_t)e * NG;
        char* base = (char*)ea_lds + row * 128;
        int swz = (row & 7) << 4;
#pragma unroll
        for (int p = 0; p < 8; ++p) {
            int k = q * 16 + p * 2;
            float2 v = make_float2(0.f, 0.f);
            if (k < NG) v = *(const float2*)(rp + k);
            uint pk = (uint)f2b(v.x) | ((uint)f2b(v.y) << 16);
            *(uint*)(base + ((k * 2) ^ swz)) = pk;
        }
    }
    if (tid < 64)
        ccs[tid] = 0.5f * (cosf(ew[seid[e0 + tid]] * PI_OVER_CUTOFF) + 1.0f);
    __syncthreads();

    const int wv = tid >> 6;
    const int l = tid & 63;
    const int l15 = l & 15, lhi = l >> 4;
    const int arow = wv * 16 + l15;
    const int aswz = (arow & 7) << 4;

    // ---- layer 1: T = relu(EA @ w1 + b1), K=64 ----
    bf16x8 a1[2];
    {
        const char* eab = (const char*)ea_lds + arow * 128;
        a1[0] = *(const bf16x8*)(eab + ((0 + lhi * 16) ^ aswz));
        a1[1] = *(const bf16x8*)(eab + ((64 + lhi * 16) ^ aswz));
    }
    f32x4 acc1[8];
#pragma unroll
    for (int ct = 0; ct < 8; ++ct) {
        float bb = b1[ct * 16 + l15];
        acc1[ct][0] = bb; acc1[ct][1] = bb; acc1[ct][2] = bb; acc1[ct][3] = bb;
    }
#pragma unroll
    for (int ct = 0; ct < 8; ++ct)
#pragma unroll
        for (int ks = 0; ks < 2; ++ks) {
            bf16x8 bfr = *(const bf16x8*)(w1p + ((size_t)(ct * 2 + ks) * 64 + l) * 8);
            acc1[ct] = __builtin_amdgcn_mfma_f32_16x16x32_bf16(a1[ks], bfr, acc1[ct], 0, 0, 0);
        }
#pragma unroll
    for (int ct = 0; ct < 8; ++ct)
#pragma unroll
        for (int q = 0; q < 4; ++q) {
            int row = wv * 16 + lhi * 4 + q;
            int col = ct * 16 + l15;
            *(ushort*)((char*)t_lds + ((row * 256 + col * 2) ^ ((row & 7) << 4))) =
                f2b(fmaxf(acc1[ct][q], 0.f));
        }
    __syncthreads();

    // ---- layer 2: W = T @ w2 + b2, K=128 ----
    bf16x8 a2[4];
    {
        const char* tb = (const char*)t_lds + arow * 256;
#pragma unroll
        for (int ks = 0; ks < 4; ++ks)
            a2[ks] = *(const bf16x8*)(tb + ((ks * 64 + lhi * 16) ^ aswz));
    }
    f32x4 acc2[8];
#pragma unroll
    for (int ct = 0; ct < 8; ++ct) {
        float bb = b2[ct * 16 + l15];
        acc2[ct][0] = bb; acc2[ct][1] = bb; acc2[ct][2] = bb; acc2[ct][3] = bb;
    }
#pragma unroll
    for (int ct = 0; ct < 8; ++ct)
#pragma unroll
        for (int ks = 0; ks < 4; ++ks) {
            bf16x8 bfr = *(const bf16x8*)(w2p + ((size_t)(ct * 4 + ks) * 64 + l) * 8);
            acc2[ct] = __builtin_amdgcn_mfma_f32_16x16x32_bf16(a2[ks], bfr, acc2[ct], 0, 0, 0);
        }

    // ---- epilogue: cutoff scale, store bf16 at CSR slot (linear) ----
    float ccr[4];
#pragma unroll
    for (int q = 0; q < 4; ++q) ccr[q] = ccs[wv * 16 + lhi * 4 + q];
#pragma unroll
    for (int ct = 0; ct < 8; ++ct)
#pragma unroll
        for (int q = 0; q < 4; ++q) {
            int row = wv * 16 + lhi * 4 + q;
            int col = ct * 16 + l15;
            Wout[(size_t)(e0 + row) * NF + col] = f2b(acc2[ct][q] * ccr[q]);
        }
}

// ===== vectorized gather: agg[d] = sum_slot W[slot] * xf[ssrc[slot]]  (bf16) =====
// 16 dst per block, 16 threads per dst, 8 channels per thread.
__global__ __launch_bounds__(256) void gather_k(
    const int* __restrict__ startx, const int* __restrict__ deg,
    const int* __restrict__ ssrc,
    const ushort* __restrict__ Wbuf, const ushort* __restrict__ xfb,
    ushort* __restrict__ aggb)
{
    int d = blockIdx.x * 16 + (threadIdx.x >> 4);
    int c0 = (threadIdx.x & 15) * 8;
    int s0 = startx[d];
    int n = deg[d];
    float acc[8] = {0.f, 0.f, 0.f, 0.f, 0.f, 0.f, 0.f, 0.f};
    for (int i = 0; i < n; ++i) {
        int slot = s0 + i;
        int src = ssrc[slot];
        uint4 wv4 = *(const uint4*)(Wbuf + (size_t)slot * NF + c0);
        uint4 xv4 = *(const uint4*)(xfb + (size_t)src * NF + c0);
        const ushort* wu = (const ushort*)&wv4;
        const ushort* xu = (const ushort*)&xv4;
#pragma unroll
        for (int j = 0; j < 8; ++j)
            acc[j] = fmaf(b2f(wu[j]), b2f(xu[j]), acc[j]);
    }
    ushort o[8];
#pragma unroll
    for (int j = 0; j < 8; ++j) o[j] = f2b(acc[j]);
    *(uint4*)(aggb + (size_t)d * NF + c0) = *(uint4*)o;
}

// ============ fallback: round-1 fused atomic kernel (small ws only) ==========
__global__ __launch_bounds__(256) void edge_mlp_scatter(
    const float* __restrict__ EA, const float* __restrict__ w1,
    const float* __restrict__ b1, const float* __restrict__ w2,
    const float* __restrict__ b2, const float* __restrict__ ew,
    const int* __restrict__ ei, const float* __restrict__ xf,
    float* __restrict__ agg)
{
    __shared__ float w1s[NG * NF];
    __shared__ float b1s[NF];
    __shared__ float w2s[NF * NF];
    __shared__ float b2s[NF];
    __shared__ float eas[64 * NG];
    __shared__ float ts[64 * 132];

    const int tid = threadIdx.x;
    for (int i = tid; i < NG * NF / 4; i += 256)
        ((float4*)w1s)[i] = ((const float4*)w1)[i];
    for (int i = tid; i < NF * NF / 4; i += 256)
        ((float4*)w2s)[i] = ((const float4*)w2)[i];
    if (tid < NF / 4) ((float4*)b1s)[tid] = ((const float4*)b1)[tid];
    else if (tid < NF / 2) ((float4*)b2s)[tid - NF / 4] = ((const float4*)b2)[tid - NF / 4];

    const int e0 = blockIdx.x * 64;
    for (int i = tid; i < 64 * NG / 4; i += 256)
        ((float4*)eas)[i] = ((const float4*)(EA + (size_t)e0 * NG))[i];
    __syncthreads();

    const int tr = tid >> 4;
    const int tc = tid & 15;

    float acc[4][8];
#pragma unroll
    for (int i = 0; i < 4; ++i)
#pragma unroll
        for (int j = 0; j < 8; ++j) acc[i][j] = b1s[tc * 8 + j];
    for (int k = 0; k < NG; ++k) {
        float b[8];
        *(float4*)&b[0] = *(const float4*)&w1s[k * NF + tc * 8];
        *(float4*)&b[4] = *(const float4*)&w1s[k * NF + tc * 8 + 4];
#pragma unroll
        for (int i = 0; i < 4; ++i) {
            float a = eas[(tr * 4 + i) * NG + k];
#pragma unroll
            for (int j = 0; j < 8; ++j) acc[i][j] = fmaf(a, b[j], acc[i][j]);
        }
    }
#pragma unroll
    for (int i = 0; i < 4; ++i)
#pragma unroll
        for (int jj = 0; jj < 2; ++jj) {
            float4 v;
            v.x = fmaxf(acc[i][jj * 4 + 0], 0.f);
            v.y = fmaxf(acc[i][jj * 4 + 1], 0.f);
            v.z = fmaxf(acc[i][jj * 4 + 2], 0.f);
            v.w = fmaxf(acc[i][jj * 4 + 3], 0.f);
            *(float4*)&ts[(tr * 4 + i) * 132 + tc * 8 + jj * 4] = v;
        }
    __syncthreads();

    float acc2[4][8];
#pragma unroll
    for (int i = 0; i < 4; ++i)
#pragma unroll
        for (int j = 0; j < 8; ++j) acc2[i][j] = b2s[tc * 8 + j];
    for (int k = 0; k < NF; ++k) {
        float b[8];
        *(float4*)&b[0] = *(const float4*)&w2s[k * NF + tc * 8];
        *(float4*)&b[4] = *(const float4*)&w2s[k * NF + tc * 8 + 4];
#pragma unroll
        for (int i = 0; i < 4; ++i) {
            float a = ts[(tr * 4 + i) * 132 + k];
#pragma unroll
            for (int j = 0; j < 8; ++j) acc2[i][j] = fmaf(a, b[j], acc2[i][j]);
        }
    }

#pragma unroll
    for (int i = 0; i < 4; ++i) {
        int e = e0 + tr * 4 + i;
        int src = ei[e];
        int dst = ei[ECONF + e];
        float cc = 0.5f * (cosf(ew[e] * PI_OVER_CUTOFF) + 1.0f);
        float4 x0 = *(const float4*)(xf + (size_t)src * NF + tc * 8);
        float4 x1 = *(const float4*)(xf + (size_t)src * NF + tc * 8 + 4);
        float xv[8] = { x0.x, x0.y, x0.z, x0.w, x1.x, x1.y, x1.z, x1.w };
        float* ap = agg + (size_t)dst * NF + tc * 8;
#pragma unroll
        for (int j = 0; j < 8; ++j)
            atomicAdd(ap + j, cc * acc2[i][j] * xv[j]);
    }
}

// ================= small kernels =================
__global__ __launch_bounds__(256) void seg_max_k(const float* __restrict__ x,
                                                 float* __restrict__ xagg)
{
    int g = blockIdx.x;
    int c = threadIdx.x;
    float m = -INFINITY;
#pragma unroll
    for (int r = 0; r < NCONF / NGRAPH; ++r)
        m = fmaxf(m, x[((size_t)g * (NCONF / NGRAPH) + r) * HIDDEN + c]);
    xagg[(size_t)g * HIDDEN + c] = m;
}

__global__ __launch_bounds__(256) void gin_edge_k(const float* __restrict__ xagg,
                                                  const float* __restrict__ bemb,
                                                  const int* __restrict__ eig,
                                                  const int* __restrict__ eag,
                                                  float* __restrict__ aggg)
{
    int e = blockIdx.x;
    int c = threadIdx.x;
    int sg = eig[e];
    int dg = eig[EGRAPH + e];
    int f0 = eag[e * 3 + 0];
    int f1 = eag[e * 3 + 1];
    int f2 = eag[e * 3 + 2];
    float v = xagg[(size_t)sg * HIDDEN + c]
            + bemb[(0 * 5 + f0) * HIDDEN + c]
            + bemb[(1 * 5 + f1) * HIDDEN + c]
            + bemb[(2 * 5 + f2) * HIDDEN + c];
    v = fmaxf(v, 0.f);
    atomicAdd(&aggg[(size_t)dg * HIDDEN + c], v);
}

__global__ __launch_bounds__(256) void gin_t_k(const float* __restrict__ xagg,
                                               const float* __restrict__ aggg,
                                               const float* __restrict__ epsp,
                                               float* __restrict__ t)
{
    int idx = blockIdx.x * 256 + threadIdx.x;
    float e1 = 1.f + epsp[0];
    float4 a = ((const float4*)xagg)[idx];
    float4 g = ((const float4*)aggg)[idx];
    ((float4*)t)[idx] = make_float4(e1 * a.x + g.x, e1 * a.y + g.y,
                                    e1 * a.z + g.z, e1 * a.w + g.w);
}

__global__ __launch_bounds__(256) void bn_stats_k(const float* __restrict__ u, int M,
                                                  float* __restrict__ sums)
{
    int c = threadIdx.x;
    int r0 = blockIdx.x * 256;
    int rend = min(r0 + 256, M);
    float s = 0.f, s2 = 0.f;
    for (int r = r0; r < rend; ++r) {
        float v = u[(size_t)r * HIDDEN + c];
        s += v;
        s2 = fmaf(v, v, s2);
    }
    atomicAdd(&sums[c], s);
    atomicAdd(&sums[HIDDEN + c], s2);
}

__global__ __launch_bounds__(256) void bn_final_k(const float* __restrict__ sums,
                                                  const float* __restrict__ g,
                                                  const float* __restrict__ b,
                                                  int M, float* __restrict__ ss)
{
    int c = threadIdx.x;
    float mean = sums[c] / (float)M;
    float var = sums[HIDDEN + c] / (float)M - mean * mean;
    float sc = g[c] / sqrtf(var + 1e-5f);
    ss[c] = sc;
    ss[HIDDEN + c] = b[c] - mean * sc;
}

template<bool RELU>
__global__ __launch_bounds__(256) void bn_apply_k(const float* __restrict__ u,
                                                  const float* __restrict__ ss,
                                                  float* __restrict__ out)
{
    int idx = blockIdx.x * 256 + threadIdx.x;
    int c4 = (idx & (HIDDEN / 4 - 1)) * 4;
    float4 v = ((const float4*)u)[idx];
    float4 sc = *(const float4*)&ss[c4];
    float4 sh = *(const float4*)&ss[HIDDEN + c4];
    float4 o = make_float4(v.x * sc.x + sh.x, v.y * sc.y + sh.y,
                           v.z * sc.z + sh.z, v.w * sc.w + sh.w);
    if (RELU) {
        o.x = fmaxf(o.x, 0.f); o.y = fmaxf(o.y, 0.f);
        o.z = fmaxf(o.z, 0.f); o.w = fmaxf(o.w, 0.f);
    }
    ((float4*)out)[idx] = o;
}

// ================= launch =================
extern "C" void kernel_launch(void* const* d_in, const int* in_sizes, int n_in,
                              void* d_out, int out_size, void* d_ws, size_t ws_size,
                              hipStream_t stream)
{
    const float* x        = (const float*)d_in[0];
    const int*   cnb      = (const int*)d_in[1];
    const int*   eic      = (const int*)d_in[2];
    const float* ewc      = (const float*)d_in[3];
    const float* eac      = (const float*)d_in[4];
    const int*   eig      = (const int*)d_in[5];
    const int*   eag      = (const int*)d_in[6];
    const float* mlp_w1   = (const float*)d_in[7];
    const float* mlp_b1   = (const float*)d_in[8];
    const float* mlp_w2   = (const float*)d_in[9];
    const float* mlp_b2   = (const float*)d_in[10];
    const float* cf_lin1  = (const float*)d_in[11];
    const float* cf_lin2  = (const float*)d_in[12];
    const float* cf_lin2b = (const float*)d_in[13];
    const float* lin_w    = (const float*)d_in[14];
    const float* lin_b    = (const float*)d_in[15];
    const float* bond_emb = (const float*)d_in[16];
    const float* gin_eps  = (const float*)d_in[17];
    const float* gin_w1   = (const float*)d_in[18];
    const float* gin_b1   = (const float*)d_in[19];
    const float* bn1_g    = (const float*)d_in[20];
    const float* bn1_b    = (const float*)d_in[21];
    const float* gin_w2   = (const float*)d_in[22];
    const float* gin_b2   = (const float*)d_in[23];
    const float* bn2_g    = (const float*)d_in[24];
    const float* bn2_b    = (const float*)d_in[25];
    float* out = (float*)d_out;

    char* ws = (char*)d_ws;
    const bool big = (ws_size >= WS_NEEDED);

    if (big) {
        ushort* xfb   = (ushort*)(ws + XFB_OFF);
        ushort* aggb  = (ushort*)(ws + AGGB_OFF);
        ushort* Wbuf  = (ushort*)(ws + WBUF_OFF);
        ushort* hmidb = (ushort*)(ws + HMIDB_OFF);   // overlays Wbuf (dead after gather)
        float* xagg   = (float*)(ws + XAGG_OFF);
        float* aggg   = (float*)(ws + AGGG_OFF);
        float* tbuf   = (float*)(ws + TBUF_OFF);
        float* ubuf   = (float*)(ws + UBUF_OFF);
        float* sums1  = (float*)(ws + STATS_OFF);
        float* ss1    = sums1 + 512;
        float* sums2  = sums1 + 1024;
        float* ss2    = sums1 + 1536;
        int* deg      = (int*)(ws + DEG_OFF);
        int* startx   = (int*)(ws + START_OFF);
        int* cursor   = (int*)(ws + CURS_OFF);
        int* bsum     = (int*)(ws + BSUM_OFF);
        int* ssrc     = (int*)(ws + SSRC_OFF);
        int* seid     = (int*)(ws + SEID_OFF);
        ushort* w1p   = (ushort*)(ws + W1P_OFF);
        ushort* w2p   = (ushort*)(ws + W2P_OFF);
        ushort* l1p   = (ushort*)(ws + L1P_OFF);
        ushort* l2p   = (ushort*)(ws + L2P_OFF);
        ushort* lwp   = (ushort*)(ws + LWP_OFF);
        float* gout   = aggg;

        hipMemsetAsync(aggg, 0, (size_t)NGRAPH * HIDDEN * 4, stream);
        hipMemsetAsync(sums1, 0, 8192, stream);
        hipMemsetAsync(deg, 0, 400000, stream);
        hipMemsetAsync(cursor, 0, 400000, stream);

        // pack weights into MFMA fragment order
        prep_w_k<<<12, 256, 0, stream>>>(mlp_w1, mlp_w2, w1p, w2p);
        prep_pack_k<<<16, 256, 0, stream>>>(cf_lin1, l1p, 256, 128);
        prep_pack_k<<<16, 256, 0, stream>>>(cf_lin2, l2p, 128, 256);
        prep_pack_k<<<32, 256, 0, stream>>>(lin_w,   lwp, 256, 256);

        // GIN pooling (reads x only)
        seg_max_k<<<NGRAPH, 256, 0, stream>>>(x, xagg);

        // xf = x @ cf_lin1  (bf16 out)
        gemm_mfma<0, 256, 128, float><<<1563, 256, 0, stream>>>(
            x, l1p, xfb, NCONF, nullptr, nullptr, nullptr, nullptr);

        // CSR by dst
        hist_k<<<(ECONF + 255) / 256, 256, 0, stream>>>(eic, deg);
        scanA_k<<<NBLK, 256, 0, stream>>>(deg, startx, bsum);
        scanB_k<<<1, 512, 0, stream>>>(bsum);
        scanC_k<<<NBLK, 256, 0, stream>>>(startx, bsum);
        fill_csr_k<<<(ECONF + 255) / 256, 256, 0, stream>>>(eic, startx, cursor, ssrc, seid);

        // MFMA filter MLP -> bf16 W in CSR order (cutoff folded)
        edge_mlp_mfma_k<<<ECONF / 64, 256, 0, stream>>>(eac, w1p, mlp_b1, w2p, mlp_b2,
                                                        ewc, seid, Wbuf);
        // vectorized deterministic gather
        gather_k<<<NCONF / 16, 256, 0, stream>>>(startx, deg, ssrc, Wbuf, xfb, aggb);

        // hmid = relu(agg @ cf_lin2 + b)  (bf16 out, overlays Wbuf)
        gemm_mfma<1, 128, 256, ushort><<<1563, 256, 0, stream>>>(
            aggb, l2p, hmidb, NCONF, cf_lin2b, nullptr, nullptr, nullptr);

        // GIN branch (fp32)
        gin_edge_k<<<EGRAPH, 256, 0, stream>>>(xagg, bond_emb, eig, eag, aggg);
        gin_t_k<<<NGRAPH * HIDDEN / 4 / 256, 256, 0, stream>>>(xagg, aggg, gin_eps, tbuf);
        gemm128<0><<<dim3(79, 2), 256, 0, stream>>>(tbuf, gin_w1, ubuf, NGRAPH, HIDDEN,
                                                    HIDDEN, gin_b1, nullptr, nullptr, nullptr);
        bn_stats_k<<<(NGRAPH + 255) / 256, 256, 0, stream>>>(ubuf, NGRAPH, sums1);
        bn_final_k<<<1, 256, 0, stream>>>(sums1, bn1_g, bn1_b, NGRAPH, ss1);
        bn_apply_k<true><<<NGRAPH * HIDDEN / 4 / 256, 256, 0, stream>>>(ubuf, ss1, tbuf);
        gemm128<0><<<dim3(79, 2), 256, 0, stream>>>(tbuf, gin_w2, ubuf, NGRAPH, HIDDEN,
                                                    HIDDEN, gin_b2, nullptr, nullptr, nullptr);
        bn_stats_k<<<(NGRAPH + 255) / 256, 256, 0, stream>>>(ubuf, NGRAPH, sums2);
        bn_final_k<<<1, 256, 0, stream>>>(sums2, bn2_g, bn2_b, NGRAPH, ss2);
        bn_apply_k<false><<<NGRAPH * HIDDEN / 4 / 256, 256, 0, stream>>>(ubuf, ss2, gout);

        // out = x + hmid @ lin_w + lin_b + gout[batch]
        gemm_mfma<2, 256, 256, ushort><<<1563, 256, 0, stream>>>(
            hmidb, lwp, out, NCONF, lin_b, x, gout, cnb);
    } else {
        // -------- fallback: round-1 fp32 path --------
        float* agg   = (float*)(ws + S_AGG_OFF);
        float* xf    = (float*)(ws + S_XF_OFF);
        float* hmid  = (float*)(ws + S_HMID_OFF);
        float* xagg  = (float*)(ws + S_XAGG_OFF);
        float* aggg  = (float*)(ws + S_AGGG_OFF);
        float* tbuf  = (float*)(ws + S_TBUF_OFF);
        float* ubuf  = (float*)(ws + S_UBUF_OFF);
        float* sums1 = (float*)(ws + S_STATS_OFF);
        float* ss1   = sums1 + 512;
        float* sums2 = sums1 + 1024;
        float* ss2   = sums1 + 1536;
        float* gout  = aggg;

        hipMemsetAsync(agg, 0, (size_t)NCONF * NF * 4, stream);
        hipMemsetAsync(aggg, 0, (size_t)NGRAPH * HIDDEN * 4, stream);
        hipMemsetAsync(sums1, 0, 8192, stream);

        seg_max_k<<<NGRAPH, 256, 0, stream>>>(x, xagg);
        gemm128<0><<<dim3(782, 1), 256, 0, stream>>>(x, cf_lin1, xf, NCONF, NF, HIDDEN,
                                                     nullptr, nullptr, nullptr, nullptr);
        edge_mlp_scatter<<<ECONF / 64, 256, 0, stream>>>(eac, mlp_w1, mlp_b1, mlp_w2,
                                                         mlp_b2, ewc, eic, xf, agg);
        gemm128<1><<<dim3(782, 2), 256, 0, stream>>>(agg, cf_lin2, hmid, NCONF, HIDDEN,
                                                     NF, cf_lin2b, nullptr, nullptr, nullptr);
        gin_edge_k<<<EGRAPH, 256, 0, stream>>>(xagg, bond_emb, eig, eag, aggg);
        gin_t_k<<<NGRAPH * HIDDEN / 4 / 256, 256, 0, stream>>>(xagg, aggg, gin_eps, tbuf);
        gemm128<0><<<dim3(79, 2), 256, 0, stream>>>(tbuf, gin_w1, ubuf, NGRAPH, HIDDEN,
                                                    HIDDEN, gin_b1, nullptr, nullptr, nullptr);
        bn_stats_k<<<(NGRAPH + 255) / 256, 256, 0, stream>>>(ubuf, NGRAPH, sums1);
        bn_final_k<<<1, 256, 0, stream>>>(sums1, bn1_g, bn1_b, NGRAPH, ss1);
        bn_apply_k<true><<<NGRAPH * HIDDEN / 4 / 256, 256, 0, stream>>>(ubuf, ss1, tbuf);
        gemm128<0><<<dim3(79, 2), 256, 0, stream>>>(tbuf, gin_w2, ubuf, NGRAPH, HIDDEN,
                                                    HIDDEN, gin_b2, nullptr, nullptr, nullptr);
        bn_stats_k<<<(NGRAPH + 255) / 256, 256, 0, stream>>>(ubuf, NGRAPH, sums2);
        bn_final_k<<<1, 256, 0, stream>>>(sums2, bn2_g, bn2_b, NGRAPH, ss2);
        bn_apply_k<false><<<NGRAPH * HIDDEN / 4 / 256, 256, 0, stream>>>(ubuf, ss2, gout);
        gemm128<2><<<dim3(782, 2), 256, 0, stream>>>(hmid, lin_w, out, NCONF, HIDDEN,
                                                     HIDDEN, lin_b, x, gout, cnb);
    }
}